// Round 13
// baseline (995.871 us; speedup 1.0000x reference)
//
#include <hip/hip_runtime.h>
#include <hip/hip_bf16.h>

#define B 32
#define H 128
#define L 4096
#define NC 32
#define NL 6
#define NCHUNK 128

typedef __hip_bfloat16 bf16;
typedef __attribute__((ext_vector_type(8))) short short8v;   // 8 bf16 (4 VGPR)
typedef __attribute__((ext_vector_type(4))) float floatx4;   // MFMA C/D

__device__ __forceinline__ float b2f(bf16 v) { return __bfloat162float(v); }
__device__ __forceinline__ float bu2f(unsigned int u) {
  union { unsigned int i; float f; } v; v.i = u << 16; return v.f;
}
// float -> bf16 bits, round-to-nearest-even
__device__ __forceinline__ unsigned short f2bs(float f) {
  unsigned u = __float_as_uint(f);
  u = (u + 0x7fffu + ((u >> 16) & 1u)) >> 16;
  return (unsigned short)u;
}

// ---------------- encoder ----------------
__global__ void encoder_kernel(const float* __restrict__ x, const float* __restrict__ enc_W,
                               const float* __restrict__ enc_b, bf16* __restrict__ h) {
  int blk = blockIdx.x;
  int b = blk >> 7, ch = blk & 127;
  float w0 = enc_W[ch];
  float w1 = enc_W[H + ch];
  float bb = enc_b[ch];
  const float* x0 = x + (size_t)b * 2 * L;
  const float* x1 = x0 + L;
  bf16* out = h + ((size_t)b * H + ch) * L;
  for (int l = threadIdx.x; l < L; l += blockDim.x)
    out[l] = __float2bfloat16(x0[l] * w0 + x1[l] * w1 + bb);
}

// Wb[l][hl][o][k]: hi/lo bf16 split of out_W[l][o][k]; per-layer stride 65536
// (glu uses only the hi plane)
__global__ void w_prep_kernel(const float* __restrict__ out_W, unsigned short* __restrict__ Wb) {
  int idx = blockIdx.x * 256 + threadIdx.x;
  if (idx >= NL * 2 * H * H) return;
  int l = idx / (2 * H * H);
  int rem = idx % (2 * H * H);
  float v = out_W[idx];
  unsigned short hi = f2bs(v);
  unsigned short lo = f2bs(v - bu2f(hi));
  Wb[(size_t)l * 65536 + rem] = hi;
  Wb[(size_t)l * 65536 + 32768 + rem] = lo;
}

// ---------------- per-(layer,h) B-matrix precompute ----------------
__global__ __launch_bounds__(256) void s4d_prep_kernel(
    const float* __restrict__ log_dt, const float* __restrict__ C_re,
    const float* __restrict__ C_im, const float* __restrict__ log_A_real,
    const float* __restrict__ A_imag, const float* __restrict__ Dp,
    unsigned short* __restrict__ Bg, float2* __restrict__ wTg, int layer) {
  __shared__ float2 dta_s[NC], cd_s[NC];
  __shared__ float K_s[32];
  int h = blockIdx.x, tid = threadIdx.x;
  if (tid < NC) {
    int n = tid, base = (layer * H + h) * NC + n;
    float dt = expf(log_dt[layer * H + h]);
    float Are = -expf(log_A_real[base]);
    float Aim = A_imag[base];
    float dre = dt * Are, dim = dt * Aim;
    float er = expf(dre);
    float wre = er * cosf(dim), wim = er * sinf(dim);
    float emre = wre - 1.f, emim = wim;   // expm1(dtA)
    float cre = C_re[base], cim = C_im[base];
    float nre = cre * emre - cim * emim, nim = cre * emim + cim * emre;
    float den = Are * Are + Aim * Aim;
    dta_s[n] = make_float2(dre, dim);
    cd_s[n] = make_float2((nre * Are + nim * Aim) / den, (nim * Are - nre * Aim) / den);
    float e32 = expf(dre * 32.f);
    wTg[h * NC + n] = make_float2(e32 * cosf(dim * 32.f), e32 * sinf(dim * 32.f));
  }
  __syncthreads();
  if (tid < 32) {  // K[tau] = 2 sum_n Re(cd_n w_n^tau)
    float acc = 0.f;
    float tau = (float)tid;
    for (int n = 0; n < NC; ++n) {
      float e = expf(dta_s[n].x * tau);
      float pr = e * cosf(dta_s[n].y * tau), pi = e * sinf(dta_s[n].y * tau);
      acc += cd_s[n].x * pr - cd_s[n].y * pi;
    }
    K_s[tid] = 2.f * acc;
  }
  __syncthreads();
  unsigned short* bb = Bg + (size_t)h * 12288;
  float Dv = Dp[layer * H + h];
  #pragma unroll
  for (int i = 0; i < 8; ++i) {     // VT: 2048 entries
    int idx = tid + i * 256;
    int n2 = idx >> 5, t = idx & 31, n = n2 >> 1;
    float k = (float)(31 - t);
    float e = expf(dta_s[n].x * k);
    float v = (n2 & 1) ? e * sinf(dta_s[n].y * k) : e * cosf(dta_s[n].y * k);
    unsigned short hi = f2bs(v);
    unsigned short lo = f2bs(v - bu2f(hi));
    bb[n2 * 40 + t] = hi;
    bb[2560 + n2 * 40 + t] = lo;
  }
  #pragma unroll
  for (int i = 0; i < 4; ++i) {     // KT: 1024 entries
    int idx = tid + i * 256;
    int t = idx >> 5, m = idx & 31;
    float v = (m > t) ? 0.f : (K_s[t - m] + (m == t ? Dv : 0.f));
    unsigned short hi = f2bs(v);
    unsigned short lo = f2bs(v - bu2f(hi));
    bb[5120 + t * 40 + m] = hi;
    bb[6400 + t * 40 + m] = lo;
  }
  #pragma unroll
  for (int i = 0; i < 8; ++i) {     // WT: 2048 entries
    int idx = tid + i * 256;
    int t = idx >> 6, k = idx & 63, n = k >> 1;
    float tp = (float)(t + 1);
    float e = expf(dta_s[n].x * tp);
    float pr = e * cosf(dta_s[n].y * tp), pi = e * sinf(dta_s[n].y * tp);
    float cwr = cd_s[n].x * pr - cd_s[n].y * pi;
    float cwi = cd_s[n].x * pi + cd_s[n].y * pr;
    float v = (k & 1) ? -2.f * cwi : 2.f * cwr;
    unsigned short hi = f2bs(v);
    unsigned short lo = f2bs(v - bu2f(hi));
    bb[7680 + t * 72 + k] = hi;
    bb[9984 + t * 72 + k] = lo;
  }
}

// ---------------- S4D conv v4: B-frags direct from L2, 51.5 KB LDS -> 3 blocks/CU (R11, proven) ----------------
__global__ __launch_bounds__(256, 3) void s4d_conv4_kernel(
    const bf16* __restrict__ u_g, bf16* __restrict__ y_g,
    const unsigned short* __restrict__ Bg, const float2* __restrict__ wTg) {
  static __shared__ char __align__(16) sm[51456];
  constexpr int O_U = 0;
  constexpr int O_SH = 10240;
  constexpr int O_SL = 28672;
  constexpr int O_WT = 47104;
  constexpr int O_GE = 47360;
  constexpr int O_GT = 49408;

  int tid = threadIdx.x;
  int lane = tid & 63, wv = tid >> 6;
  int r15 = lane & 15, quad = lane >> 4;
  int bh = blockIdx.x, hh = bh & 127;
  const char* bg0 = (const char*)(Bg + (size_t)hh * 12288);

  {
    const uint4* ug = (const uint4*)(u_g + (size_t)bh * L);
    #pragma unroll
    for (int r = 0; r < 2; ++r) {
      int idx = tid + r * 256;
      *(uint4*)(sm + O_U + (idx >> 2) * 80 + (idx & 3) * 16) = ug[idx];
    }
  }
  if (tid < 32) *(float2*)(sm + O_WT + tid * 8) = wTg[hh * 32 + tid];

  short8v bvh[4], bvl[4];
  #pragma unroll
  for (int nt = 0; nt < 4; ++nt) {
    bvh[nt] = *(const short8v*)(bg0 + 0    + (nt * 16 + r15) * 80 + quad * 16);
    bvl[nt] = *(const short8v*)(bg0 + 5120 + (nt * 16 + r15) * 80 + quad * 16);
  }
  __syncthreads();

  short8v aU0 = *(const short8v*)(sm + O_U + ((wv * 2 + 0) * 16 + r15) * 80 + quad * 16);
  short8v aU1 = *(const short8v*)(sm + O_U + ((wv * 2 + 1) * 16 + r15) * 80 + quad * 16);
  floatx4 cp[2][4];
  #pragma unroll
  for (int mt = 0; mt < 2; ++mt)
    #pragma unroll
    for (int nt = 0; nt < 4; ++nt) cp[mt][nt] = (floatx4){0.f, 0.f, 0.f, 0.f};
  #pragma unroll
  for (int nt = 0; nt < 4; ++nt) {
    cp[0][nt] = __builtin_amdgcn_mfma_f32_16x16x32_bf16(aU0, bvh[nt], cp[0][nt], 0, 0, 0);
    cp[0][nt] = __builtin_amdgcn_mfma_f32_16x16x32_bf16(aU0, bvl[nt], cp[0][nt], 0, 0, 0);
    cp[1][nt] = __builtin_amdgcn_mfma_f32_16x16x32_bf16(aU1, bvh[nt], cp[1][nt], 0, 0, 0);
    cp[1][nt] = __builtin_amdgcn_mfma_f32_16x16x32_bf16(aU1, bvl[nt], cp[1][nt], 0, 0, 0);
  }
  #pragma unroll
  for (int mt = 0; mt < 2; ++mt)
    #pragma unroll
    for (int nt = 0; nt < 4; ++nt) {
      int n2 = nt * 16 + r15;
      int off = ((n2 & 1) ? O_SL : O_SH) + (n2 >> 1) * 4;
      #pragma unroll
      for (int rg = 0; rg < 4; ++rg) {
        int c = (wv * 2 + mt) * 16 + quad * 4 + rg;
        *(float*)(sm + off + c * 144) = cp[mt][nt][rg];
      }
    }
  __syncthreads();

  {
    int g = tid >> 5, n = tid & 31;
    float2 wt = *(const float2*)(sm + O_WT + n * 8);
    float rr = 0.f, ri = 0.f;
    for (int k = 0; k < 16; ++k) {
      int c = g * 16 + k;
      float* pr = (float*)(sm + O_SH + c * 144 + n * 4);
      float* pi = (float*)(sm + O_SL + c * 144 + n * 4);
      float pre_ = *pr, pim_ = *pi;
      *pr = rr; *pi = ri;
      float nr = wt.x * rr - wt.y * ri + pre_;
      ri = wt.x * ri + wt.y * rr + pim_;
      rr = nr;
    }
    *(float2*)(sm + O_GT + (g * 32 + n) * 8) = make_float2(rr, ri);
  }
  __syncthreads();
  if (tid < 32) {
    float2 wt = *(const float2*)(sm + O_WT + tid * 8);
    float w2r = wt.x * wt.x - wt.y * wt.y,   w2i = 2.f * wt.x * wt.y;
    float w4r = w2r * w2r - w2i * w2i,       w4i = 2.f * w2r * w2i;
    float w8r = w4r * w4r - w4i * w4i,       w8i = 2.f * w4r * w4i;
    float w16r = w8r * w8r - w8i * w8i,      w16i = 2.f * w8r * w8i;
    float rr = 0.f, ri = 0.f;
    for (int g = 0; g < 8; ++g) {
      *(float2*)(sm + O_GE + (g * 32 + tid) * 8) = make_float2(rr, ri);
      float2 gt = *(const float2*)(sm + O_GT + (g * 32 + tid) * 8);
      float nr = w16r * rr - w16i * ri + gt.x;
      ri = w16r * ri + w16i * rr + gt.y;
      rr = nr;
    }
  }
  __syncthreads();
  {
    int g = tid >> 5, n = tid & 31;
    float2 wt = *(const float2*)(sm + O_WT + n * 8);
    float2 ge = *(const float2*)(sm + O_GE + (g * 32 + n) * 8);
    float ar = ge.x, ai = ge.y;
    for (int k = 0; k < 16; ++k) {
      int c = g * 16 + k;
      char* ph = sm + O_SH + c * 144 + n * 4;
      char* pl = sm + O_SL + c * 144 + n * 4;
      float er = *(const float*)ph + ar;
      float ei = *(const float*)pl + ai;
      unsigned short hr = f2bs(er), him = f2bs(ei);
      *(unsigned*)ph = ((unsigned)him << 16) | hr;
      *(unsigned*)pl = ((unsigned)f2bs(ei - bu2f(him)) << 16) | f2bs(er - bu2f(hr));
      float nr = ar * wt.x - ai * wt.y;
      ai = ar * wt.y + ai * wt.x;
      ar = nr;
    }
  }
  __syncthreads();

  floatx4 acc[2][2];
  #pragma unroll
  for (int mt = 0; mt < 2; ++mt)
    #pragma unroll
    for (int nt = 0; nt < 2; ++nt) acc[mt][nt] = (floatx4){0.f, 0.f, 0.f, 0.f};
  #pragma unroll
  for (int nt = 0; nt < 2; ++nt) {
    short8v kh = *(const short8v*)(bg0 + 10240 + (nt * 16 + r15) * 80 + quad * 16);
    short8v kl = *(const short8v*)(bg0 + 12800 + (nt * 16 + r15) * 80 + quad * 16);
    acc[0][nt] = __builtin_amdgcn_mfma_f32_16x16x32_bf16(aU0, kh, acc[0][nt], 0, 0, 0);
    acc[0][nt] = __builtin_amdgcn_mfma_f32_16x16x32_bf16(aU0, kl, acc[0][nt], 0, 0, 0);
    acc[1][nt] = __builtin_amdgcn_mfma_f32_16x16x32_bf16(aU1, kh, acc[1][nt], 0, 0, 0);
    acc[1][nt] = __builtin_amdgcn_mfma_f32_16x16x32_bf16(aU1, kl, acc[1][nt], 0, 0, 0);
  }
  #pragma unroll
  for (int ks = 0; ks < 2; ++ks) {
    short8v sh0 = *(const short8v*)(sm + O_SH + ((wv * 2 + 0) * 16 + r15) * 144 + ks * 64 + quad * 16);
    short8v sh1 = *(const short8v*)(sm + O_SH + ((wv * 2 + 1) * 16 + r15) * 144 + ks * 64 + quad * 16);
    short8v sl0 = *(const short8v*)(sm + O_SL + ((wv * 2 + 0) * 16 + r15) * 144 + ks * 64 + quad * 16);
    short8v sl1 = *(const short8v*)(sm + O_SL + ((wv * 2 + 1) * 16 + r15) * 144 + ks * 64 + quad * 16);
    #pragma unroll
    for (int nt = 0; nt < 2; ++nt) {
      short8v wh = *(const short8v*)(bg0 + 15360 + (nt * 16 + r15) * 144 + ks * 64 + quad * 16);
      short8v wl = *(const short8v*)(bg0 + 19968 + (nt * 16 + r15) * 144 + ks * 64 + quad * 16);
      acc[0][nt] = __builtin_amdgcn_mfma_f32_16x16x32_bf16(sh0, wh, acc[0][nt], 0, 0, 0);
      acc[0][nt] = __builtin_amdgcn_mfma_f32_16x16x32_bf16(sh0, wl, acc[0][nt], 0, 0, 0);
      acc[0][nt] = __builtin_amdgcn_mfma_f32_16x16x32_bf16(sl0, wh, acc[0][nt], 0, 0, 0);
      acc[1][nt] = __builtin_amdgcn_mfma_f32_16x16x32_bf16(sh1, wh, acc[1][nt], 0, 0, 0);
      acc[1][nt] = __builtin_amdgcn_mfma_f32_16x16x32_bf16(sh1, wl, acc[1][nt], 0, 0, 0);
      acc[1][nt] = __builtin_amdgcn_mfma_f32_16x16x32_bf16(sl1, wh, acc[1][nt], 0, 0, 0);
    }
  }

  #pragma unroll
  for (int mt = 0; mt < 2; ++mt)
    #pragma unroll
    for (int nt = 0; nt < 2; ++nt)
      #pragma unroll
      for (int rg = 0; rg < 4; ++rg) {
        int c = (wv * 2 + mt) * 16 + quad * 4 + rg;
        int t = nt * 16 + r15;
        float v = acc[mt][nt][rg];
        v = 0.5f * v * (1.f + erff(v * 0.70710678118654752f));
        *(unsigned short*)(sm + O_U + (c * 32 + t) * 2) = f2bs(v);
      }
  __syncthreads();
  {
    uint4* yo = (uint4*)(y_g + (size_t)bh * L);
    #pragma unroll
    for (int r = 0; r < 2; ++r) {
      int idx = tid + r * 256;
      yo[idx] = *(const uint4*)(sm + O_U + idx * 16);
    }
  }
}

// ------- pointwise conv + GLU + residual + LN v8: pt-outer W streaming (NO hoist),
//         z fp32 in registers across stats barrier, redundant per-lane mu/rv,
//         single-bf16 z tile, 54.3 KB LDS -> 3 blocks/CU, 3 barriers/tile -------
__global__ __launch_bounds__(256, 3) void glu_ln8_kernel(
    const unsigned short* __restrict__ y_g, unsigned short* __restrict__ h_g,
    const unsigned short* __restrict__ Wb,  // layer: [hi 256x128] shorts
    const float* __restrict__ ob, const float* __restrict__ lg,
    const float* __restrict__ lb) {
  static __shared__ char __align__(16) sm[54272];
  constexpr int O_Y = 0;        // y transposed [64 pos][136 ch-shorts] = 17408 B (row 272 B)
  constexpr int O_H = 17408;    // h natural  [128 ch][68 pos-shorts]  = 17408 B (row 136 B)
  constexpr int O_Z = 34816;    // z bf16     [128 ch][68 pos-shorts]  = 17408 B (row 136 B)
  constexpr int O_P = 52224;    // LN partials [4 waves][64 pos] float2 = 2048 B

  int tid = threadIdx.x;
  int wv = tid >> 6, lane = tid & 63, r15 = lane & 15, quad = lane >> 4;
  int b = blockIdx.x >> 4, seg = blockIdx.x & 15;

  // per-lane GLU biases for its channels: ch = (2wv+i)*16 + quad*4 + rg
  float ba[2][4], bgl[2][4];
  #pragma unroll
  for (int i = 0; i < 2; ++i) {
    int ch0 = (2 * wv + i) * 16 + quad * 4;
    #pragma unroll
    for (int rg = 0; rg < 4; ++rg) {
      ba[i][rg]  = ob[ch0 + rg];
      bgl[i][rg] = ob[128 + ch0 + rg];
    }
  }

  for (int t = 0; t < 4; ++t) {
    int l0 = seg * 256 + t * 64;
    // ---- stage y transposed [pos][ch]
    {
      int k = tid >> 1, half = tid & 1;
      const uint4* src = (const uint4*)(y_g + ((size_t)(b * H + k)) * L + l0 + half * 32);
      unsigned short sarr[32];
      uint4* sp = (uint4*)sarr;
      sp[0] = src[0]; sp[1] = src[1]; sp[2] = src[2]; sp[3] = src[3];
      #pragma unroll
      for (int j = 0; j < 32; ++j)
        *(unsigned short*)(sm + O_Y + (half * 32 + j) * 272 + k * 2) = sarr[j];
    }
    // ---- stage h natural [ch][pos]
    {
      #pragma unroll
      for (int i = 0; i < 4; ++i) {
        int id = tid + i * 256;           // 0..1023
        int ch = id >> 3, part = id & 7;
        uint4 v = *(const uint4*)(h_g + ((size_t)(b * H + ch)) * L + l0 + part * 8);
        *(uint4*)(sm + O_H + ch * 136 + part * 16) = v;
      }
    }
    __syncthreads();   // A

    float z[2][4][4];
    float s1[4] = {0.f, 0.f, 0.f, 0.f}, s2[4] = {0.f, 0.f, 0.f, 0.f};
    #pragma unroll
    for (int pt = 0; pt < 4; ++pt) {
      short8v bf[4];
      #pragma unroll
      for (int ks = 0; ks < 4; ++ks)
        bf[ks] = *(const short8v*)(sm + O_Y + (pt * 16 + r15) * 272 + ks * 64 + quad * 16);
      int pos = pt * 16 + r15;
      #pragma unroll
      for (int i = 0; i < 2; ++i) {
        int ch0 = (2 * wv + i) * 16 + quad * 4;
        // a-GEMM (W streamed per (pt,i) -- transient registers only)
        const unsigned short* wa = Wb + (size_t)((2 * wv + i) * 16 + r15) * 128 + quad * 8;
        floatx4 acca = (floatx4){0.f, 0.f, 0.f, 0.f};
        #pragma unroll
        for (int ks = 0; ks < 4; ++ks) {
          short8v wf = *(const short8v*)(wa + ks * 32);
          acca = __builtin_amdgcn_mfma_f32_16x16x32_bf16(wf, bf[ks], acca, 0, 0, 0);
        }
        // g-GEMM
        const unsigned short* wg = Wb + (size_t)((8 + 2 * wv + i) * 16 + r15) * 128 + quad * 8;
        floatx4 accg = (floatx4){0.f, 0.f, 0.f, 0.f};
        #pragma unroll
        for (int ks = 0; ks < 4; ++ks) {
          short8v wf = *(const short8v*)(wg + ks * 32);
          accg = __builtin_amdgcn_mfma_f32_16x16x32_bf16(wf, bf[ks], accg, 0, 0, 0);
        }
        #pragma unroll
        for (int rg = 0; rg < 4; ++rg) {
          float a = acca[rg] + ba[i][rg];
          float g = accg[rg] + bgl[i][rg];
          float zz = a / (1.f + expf(-g));
          zz += bu2f(*(const unsigned short*)(sm + O_H + (ch0 + rg) * 136 + pos * 2));
          z[i][pt][rg] = zz;
          s1[pt] += zz;
          s2[pt] += zz * zz;
        }
      }
    }
    #pragma unroll
    for (int pt = 0; pt < 4; ++pt) {
      s1[pt] += __shfl_xor(s1[pt], 16, 64); s1[pt] += __shfl_xor(s1[pt], 32, 64);
      s2[pt] += __shfl_xor(s2[pt], 16, 64); s2[pt] += __shfl_xor(s2[pt], 32, 64);
    }
    if (quad == 0) {
      #pragma unroll
      for (int pt = 0; pt < 4; ++pt)
        *(float2*)(sm + O_P + (wv * 64 + pt * 16 + r15) * 8) = make_float2(s1[pt], s2[pt]);
    }
    __syncthreads();   // B (partials visible; y_s/h_s reads complete)

    // redundant per-lane mu/rinv from partials (broadcast reads)
    float mu[4], rv[4];
    #pragma unroll
    for (int pt = 0; pt < 4; ++pt) {
      float a1 = 0.f, a2 = 0.f;
      #pragma unroll
      for (int w = 0; w < 4; ++w) {
        float2 p = *(const float2*)(sm + O_P + (w * 64 + pt * 16 + r15) * 8);
        a1 += p.x; a2 += p.y;
      }
      float m = a1 * (1.f / H);
      float var = a2 * (1.f / H) - m * m;
      if (var < 0.f) var = 0.f;
      mu[pt] = m;
      rv[pt] = rsqrtf(var + 1e-5f);
    }

    // normalize in registers, write bf16 z tile
    #pragma unroll
    for (int i = 0; i < 2; ++i) {
      int ch0 = (2 * wv + i) * 16 + quad * 4;
      #pragma unroll
      for (int rg = 0; rg < 4; ++rg) {
        float gg = lg[ch0 + rg], bb2 = lb[ch0 + rg];
        #pragma unroll
        for (int pt = 0; pt < 4; ++pt) {
          int pos = pt * 16 + r15;
          float v = (z[i][pt][rg] - mu[pt]) * rv[pt] * gg + bb2;
          *(unsigned short*)(sm + O_Z + (ch0 + rg) * 136 + pos * 2) = f2bs(v);
        }
      }
    }
    __syncthreads();   // C

    // coalesced store channel-major (uint2 LDS reads: rows are 8B-aligned)
    {
      int ch = tid >> 1, half = tid & 1;
      uint2 r[8];
      #pragma unroll
      for (int j = 0; j < 8; ++j)
        r[j] = *(const uint2*)(sm + O_Z + ch * 136 + half * 64 + j * 8);
      uint4* dst = (uint4*)(h_g + ((size_t)(b * H + ch)) * L + l0 + half * 32);
      #pragma unroll
      for (int j = 0; j < 4; ++j)
        dst[j] = make_uint4(r[2 * j].x, r[2 * j].y, r[2 * j + 1].x, r[2 * j + 1].y);
    }
    // no end barrier: next-tile staging writes O_Y/O_H (last read before B);
    // next-tile z writes happen only after next B -> store reads of O_Z are safe.
  }
}

__global__ __launch_bounds__(256) void pool_kernel(const bf16* __restrict__ h_g,
                                                   float* __restrict__ pooled) {
  int bh = blockIdx.x;
  const bf16* row = h_g + (size_t)bh * L;
  float s = 0.f;
  for (int l = threadIdx.x; l < L; l += 256) s += b2f(row[l]);
  for (int off = 32; off > 0; off >>= 1) s += __shfl_down(s, off);
  __shared__ float wsum[4];
  int lane = threadIdx.x & 63, wv = threadIdx.x >> 6;
  if (lane == 0) wsum[wv] = s;
  __syncthreads();
  if (threadIdx.x == 0)
    pooled[bh] = (wsum[0] + wsum[1] + wsum[2] + wsum[3]) * (1.f / L);
}

__global__ void head_kernel(const float* __restrict__ pooled,
                            const float* __restrict__ head_W,
                            const float* __restrict__ head_b,
                            float* __restrict__ out) {
  int tid = threadIdx.x;
  if (tid >= B * 2) return;
  int b = tid >> 1, o = tid & 1;
  float acc = head_b[o];
  for (int ch = 0; ch < H; ++ch)
    acc += pooled[b * H + ch] * head_W[ch * 2 + o];
  out[tid] = acc;
}

extern "C" void kernel_launch(void* const* d_in, const int* in_sizes, int n_in,
                              void* d_out, int out_size, void* d_ws, size_t ws_size,
                              hipStream_t stream) {
  const float* x          = (const float*)d_in[0];
  const float* enc_W      = (const float*)d_in[1];
  const float* enc_b      = (const float*)d_in[2];
  const float* log_dt     = (const float*)d_in[3];
  const float* C_re       = (const float*)d_in[4];
  const float* C_im       = (const float*)d_in[5];
  const float* log_A_real = (const float*)d_in[6];
  const float* A_imag     = (const float*)d_in[7];
  const float* Dp         = (const float*)d_in[8];
  const float* out_W      = (const float*)d_in[9];
  const float* out_b      = (const float*)d_in[10];
  const float* ln_g       = (const float*)d_in[11];
  const float* ln_b       = (const float*)d_in[12];
  const float* head_W     = (const float*)d_in[13];
  const float* head_b     = (const float*)d_in[14];

  // ws: hbuf bf16 32MB | ybuf bf16 32MB | Wb bf16 hi/lo 1.5MB | pooled | Bg 3MB | wTg
  bf16* hbuf = (bf16*)d_ws;
  bf16* ybuf = hbuf + (size_t)B * H * L;
  unsigned short* Wb = (unsigned short*)(ybuf + (size_t)B * H * L);
  float* pooled = (float*)(Wb + (size_t)NL * 65536);
  unsigned short* Bg = (unsigned short*)(pooled + B * H);
  float2* wTg = (float2*)(Bg + (size_t)12288 * H);

  encoder_kernel<<<B * H, 256, 0, stream>>>(x, enc_W, enc_b, hbuf);
  w_prep_kernel<<<(NL * 2 * H * H + 255) / 256, 256, 0, stream>>>(out_W, Wb);

  for (int layer = 0; layer < NL; ++layer) {
    s4d_prep_kernel<<<H, 256, 0, stream>>>(log_dt, C_re, C_im, log_A_real,
                                           A_imag, Dp, Bg, wTg, layer);
    s4d_conv4_kernel<<<B * H, 256, 0, stream>>>(hbuf, ybuf, Bg, wTg);
    glu_ln8_kernel<<<B * 16, 256, 0, stream>>>(
        (const unsigned short*)ybuf, (unsigned short*)hbuf,
        Wb + (size_t)layer * 65536, out_b + layer * 2 * H,
        ln_g + layer * H, ln_b + layer * H);
  }

  pool_kernel<<<B * H, 256, 0, stream>>>(hbuf, pooled);
  head_kernel<<<1, 64, 0, stream>>>(pooled, head_W, head_b, (float*)d_out);
}

// Round 14
// 892.160 us; speedup vs baseline: 1.1162x; 1.1162x over previous
//
#include <hip/hip_runtime.h>
#include <hip/hip_bf16.h>

#define B 32
#define H 128
#define L 4096
#define NC 32
#define NL 6
#define NCHUNK 128

typedef __hip_bfloat16 bf16;
typedef __attribute__((ext_vector_type(8))) short short8v;   // 8 bf16 (4 VGPR)
typedef __attribute__((ext_vector_type(4))) float floatx4;   // MFMA C/D

__device__ __forceinline__ float b2f(bf16 v) { return __bfloat162float(v); }
__device__ __forceinline__ float bu2f(unsigned int u) {
  union { unsigned int i; float f; } v; v.i = u << 16; return v.f;
}
// float -> bf16 bits, round-to-nearest-even
__device__ __forceinline__ unsigned short f2bs(float f) {
  unsigned u = __float_as_uint(f);
  u = (u + 0x7fffu + ((u >> 16) & 1u)) >> 16;
  return (unsigned short)u;
}

// ---------------- encoder ----------------
__global__ void encoder_kernel(const float* __restrict__ x, const float* __restrict__ enc_W,
                               const float* __restrict__ enc_b, bf16* __restrict__ h) {
  int blk = blockIdx.x;
  int b = blk >> 7, ch = blk & 127;
  float w0 = enc_W[ch];
  float w1 = enc_W[H + ch];
  float bb = enc_b[ch];
  const float* x0 = x + (size_t)b * 2 * L;
  const float* x1 = x0 + L;
  bf16* out = h + ((size_t)b * H + ch) * L;
  for (int l = threadIdx.x; l < L; l += blockDim.x)
    out[l] = __float2bfloat16(x0[l] * w0 + x1[l] * w1 + bb);
}

// Wb[l][hl][o][k]: hi/lo bf16 split of out_W[l][o][k]; per-layer stride 65536
// (glu uses only the hi plane)
__global__ void w_prep_kernel(const float* __restrict__ out_W, unsigned short* __restrict__ Wb) {
  int idx = blockIdx.x * 256 + threadIdx.x;
  if (idx >= NL * 2 * H * H) return;
  int l = idx / (2 * H * H);
  int rem = idx % (2 * H * H);
  float v = out_W[idx];
  unsigned short hi = f2bs(v);
  unsigned short lo = f2bs(v - bu2f(hi));
  Wb[(size_t)l * 65536 + rem] = hi;
  Wb[(size_t)l * 65536 + 32768 + rem] = lo;
}

// ---------------- per-(layer,h) B-matrix precompute ----------------
__global__ __launch_bounds__(256) void s4d_prep_kernel(
    const float* __restrict__ log_dt, const float* __restrict__ C_re,
    const float* __restrict__ C_im, const float* __restrict__ log_A_real,
    const float* __restrict__ A_imag, const float* __restrict__ Dp,
    unsigned short* __restrict__ Bg, float2* __restrict__ wTg, int layer) {
  __shared__ float2 dta_s[NC], cd_s[NC];
  __shared__ float K_s[32];
  int h = blockIdx.x, tid = threadIdx.x;
  if (tid < NC) {
    int n = tid, base = (layer * H + h) * NC + n;
    float dt = expf(log_dt[layer * H + h]);
    float Are = -expf(log_A_real[base]);
    float Aim = A_imag[base];
    float dre = dt * Are, dim = dt * Aim;
    float er = expf(dre);
    float wre = er * cosf(dim), wim = er * sinf(dim);
    float emre = wre - 1.f, emim = wim;   // expm1(dtA)
    float cre = C_re[base], cim = C_im[base];
    float nre = cre * emre - cim * emim, nim = cre * emim + cim * emre;
    float den = Are * Are + Aim * Aim;
    dta_s[n] = make_float2(dre, dim);
    cd_s[n] = make_float2((nre * Are + nim * Aim) / den, (nim * Are - nre * Aim) / den);
    float e32 = expf(dre * 32.f);
    wTg[h * NC + n] = make_float2(e32 * cosf(dim * 32.f), e32 * sinf(dim * 32.f));
  }
  __syncthreads();
  if (tid < 32) {  // K[tau] = 2 sum_n Re(cd_n w_n^tau)
    float acc = 0.f;
    float tau = (float)tid;
    for (int n = 0; n < NC; ++n) {
      float e = expf(dta_s[n].x * tau);
      float pr = e * cosf(dta_s[n].y * tau), pi = e * sinf(dta_s[n].y * tau);
      acc += cd_s[n].x * pr - cd_s[n].y * pi;
    }
    K_s[tid] = 2.f * acc;
  }
  __syncthreads();
  unsigned short* bb = Bg + (size_t)h * 12288;
  float Dv = Dp[layer * H + h];
  #pragma unroll
  for (int i = 0; i < 8; ++i) {     // VT: 2048 entries
    int idx = tid + i * 256;
    int n2 = idx >> 5, t = idx & 31, n = n2 >> 1;
    float k = (float)(31 - t);
    float e = expf(dta_s[n].x * k);
    float v = (n2 & 1) ? e * sinf(dta_s[n].y * k) : e * cosf(dta_s[n].y * k);
    unsigned short hi = f2bs(v);
    unsigned short lo = f2bs(v - bu2f(hi));
    bb[n2 * 40 + t] = hi;
    bb[2560 + n2 * 40 + t] = lo;
  }
  #pragma unroll
  for (int i = 0; i < 4; ++i) {     // KT: 1024 entries
    int idx = tid + i * 256;
    int t = idx >> 5, m = idx & 31;
    float v = (m > t) ? 0.f : (K_s[t - m] + (m == t ? Dv : 0.f));
    unsigned short hi = f2bs(v);
    unsigned short lo = f2bs(v - bu2f(hi));
    bb[5120 + t * 40 + m] = hi;
    bb[6400 + t * 40 + m] = lo;
  }
  #pragma unroll
  for (int i = 0; i < 8; ++i) {     // WT: 2048 entries
    int idx = tid + i * 256;
    int t = idx >> 6, k = idx & 63, n = k >> 1;
    float tp = (float)(t + 1);
    float e = expf(dta_s[n].x * tp);
    float pr = e * cosf(dta_s[n].y * tp), pi = e * sinf(dta_s[n].y * tp);
    float cwr = cd_s[n].x * pr - cd_s[n].y * pi;
    float cwi = cd_s[n].x * pi + cd_s[n].y * pr;
    float v = (k & 1) ? -2.f * cwi : 2.f * cwr;
    unsigned short hi = f2bs(v);
    unsigned short lo = f2bs(v - bu2f(hi));
    bb[7680 + t * 72 + k] = hi;
    bb[9984 + t * 72 + k] = lo;
  }
}

// ---------------- S4D conv v4: B-frags direct from L2, 51.5 KB LDS -> 3 blocks/CU (R11, proven) ----------------
__global__ __launch_bounds__(256, 3) void s4d_conv4_kernel(
    const bf16* __restrict__ u_g, bf16* __restrict__ y_g,
    const unsigned short* __restrict__ Bg, const float2* __restrict__ wTg) {
  static __shared__ char __align__(16) sm[51456];
  constexpr int O_U = 0;
  constexpr int O_SH = 10240;
  constexpr int O_SL = 28672;
  constexpr int O_WT = 47104;
  constexpr int O_GE = 47360;
  constexpr int O_GT = 49408;

  int tid = threadIdx.x;
  int lane = tid & 63, wv = tid >> 6;
  int r15 = lane & 15, quad = lane >> 4;
  int bh = blockIdx.x, hh = bh & 127;
  const char* bg0 = (const char*)(Bg + (size_t)hh * 12288);

  {
    const uint4* ug = (const uint4*)(u_g + (size_t)bh * L);
    #pragma unroll
    for (int r = 0; r < 2; ++r) {
      int idx = tid + r * 256;
      *(uint4*)(sm + O_U + (idx >> 2) * 80 + (idx & 3) * 16) = ug[idx];
    }
  }
  if (tid < 32) *(float2*)(sm + O_WT + tid * 8) = wTg[hh * 32 + tid];

  short8v bvh[4], bvl[4];
  #pragma unroll
  for (int nt = 0; nt < 4; ++nt) {
    bvh[nt] = *(const short8v*)(bg0 + 0    + (nt * 16 + r15) * 80 + quad * 16);
    bvl[nt] = *(const short8v*)(bg0 + 5120 + (nt * 16 + r15) * 80 + quad * 16);
  }
  __syncthreads();

  short8v aU0 = *(const short8v*)(sm + O_U + ((wv * 2 + 0) * 16 + r15) * 80 + quad * 16);
  short8v aU1 = *(const short8v*)(sm + O_U + ((wv * 2 + 1) * 16 + r15) * 80 + quad * 16);
  floatx4 cp[2][4];
  #pragma unroll
  for (int mt = 0; mt < 2; ++mt)
    #pragma unroll
    for (int nt = 0; nt < 4; ++nt) cp[mt][nt] = (floatx4){0.f, 0.f, 0.f, 0.f};
  #pragma unroll
  for (int nt = 0; nt < 4; ++nt) {
    cp[0][nt] = __builtin_amdgcn_mfma_f32_16x16x32_bf16(aU0, bvh[nt], cp[0][nt], 0, 0, 0);
    cp[0][nt] = __builtin_amdgcn_mfma_f32_16x16x32_bf16(aU0, bvl[nt], cp[0][nt], 0, 0, 0);
    cp[1][nt] = __builtin_amdgcn_mfma_f32_16x16x32_bf16(aU1, bvh[nt], cp[1][nt], 0, 0, 0);
    cp[1][nt] = __builtin_amdgcn_mfma_f32_16x16x32_bf16(aU1, bvl[nt], cp[1][nt], 0, 0, 0);
  }
  #pragma unroll
  for (int mt = 0; mt < 2; ++mt)
    #pragma unroll
    for (int nt = 0; nt < 4; ++nt) {
      int n2 = nt * 16 + r15;
      int off = ((n2 & 1) ? O_SL : O_SH) + (n2 >> 1) * 4;
      #pragma unroll
      for (int rg = 0; rg < 4; ++rg) {
        int c = (wv * 2 + mt) * 16 + quad * 4 + rg;
        *(float*)(sm + off + c * 144) = cp[mt][nt][rg];
      }
    }
  __syncthreads();

  {
    int g = tid >> 5, n = tid & 31;
    float2 wt = *(const float2*)(sm + O_WT + n * 8);
    float rr = 0.f, ri = 0.f;
    for (int k = 0; k < 16; ++k) {
      int c = g * 16 + k;
      float* pr = (float*)(sm + O_SH + c * 144 + n * 4);
      float* pi = (float*)(sm + O_SL + c * 144 + n * 4);
      float pre_ = *pr, pim_ = *pi;
      *pr = rr; *pi = ri;
      float nr = wt.x * rr - wt.y * ri + pre_;
      ri = wt.x * ri + wt.y * rr + pim_;
      rr = nr;
    }
    *(float2*)(sm + O_GT + (g * 32 + n) * 8) = make_float2(rr, ri);
  }
  __syncthreads();
  if (tid < 32) {
    float2 wt = *(const float2*)(sm + O_WT + tid * 8);
    float w2r = wt.x * wt.x - wt.y * wt.y,   w2i = 2.f * wt.x * wt.y;
    float w4r = w2r * w2r - w2i * w2i,       w4i = 2.f * w2r * w2i;
    float w8r = w4r * w4r - w4i * w4i,       w8i = 2.f * w4r * w4i;
    float w16r = w8r * w8r - w8i * w8i,      w16i = 2.f * w8r * w8i;
    float rr = 0.f, ri = 0.f;
    for (int g = 0; g < 8; ++g) {
      *(float2*)(sm + O_GE + (g * 32 + tid) * 8) = make_float2(rr, ri);
      float2 gt = *(const float2*)(sm + O_GT + (g * 32 + tid) * 8);
      float nr = w16r * rr - w16i * ri + gt.x;
      ri = w16r * ri + w16i * rr + gt.y;
      rr = nr;
    }
  }
  __syncthreads();
  {
    int g = tid >> 5, n = tid & 31;
    float2 wt = *(const float2*)(sm + O_WT + n * 8);
    float2 ge = *(const float2*)(sm + O_GE + (g * 32 + n) * 8);
    float ar = ge.x, ai = ge.y;
    for (int k = 0; k < 16; ++k) {
      int c = g * 16 + k;
      char* ph = sm + O_SH + c * 144 + n * 4;
      char* pl = sm + O_SL + c * 144 + n * 4;
      float er = *(const float*)ph + ar;
      float ei = *(const float*)pl + ai;
      unsigned short hr = f2bs(er), him = f2bs(ei);
      *(unsigned*)ph = ((unsigned)him << 16) | hr;
      *(unsigned*)pl = ((unsigned)f2bs(ei - bu2f(him)) << 16) | f2bs(er - bu2f(hr));
      float nr = ar * wt.x - ai * wt.y;
      ai = ar * wt.y + ai * wt.x;
      ar = nr;
    }
  }
  __syncthreads();

  floatx4 acc[2][2];
  #pragma unroll
  for (int mt = 0; mt < 2; ++mt)
    #pragma unroll
    for (int nt = 0; nt < 2; ++nt) acc[mt][nt] = (floatx4){0.f, 0.f, 0.f, 0.f};
  #pragma unroll
  for (int nt = 0; nt < 2; ++nt) {
    short8v kh = *(const short8v*)(bg0 + 10240 + (nt * 16 + r15) * 80 + quad * 16);
    short8v kl = *(const short8v*)(bg0 + 12800 + (nt * 16 + r15) * 80 + quad * 16);
    acc[0][nt] = __builtin_amdgcn_mfma_f32_16x16x32_bf16(aU0, kh, acc[0][nt], 0, 0, 0);
    acc[0][nt] = __builtin_amdgcn_mfma_f32_16x16x32_bf16(aU0, kl, acc[0][nt], 0, 0, 0);
    acc[1][nt] = __builtin_amdgcn_mfma_f32_16x16x32_bf16(aU1, kh, acc[1][nt], 0, 0, 0);
    acc[1][nt] = __builtin_amdgcn_mfma_f32_16x16x32_bf16(aU1, kl, acc[1][nt], 0, 0, 0);
  }
  #pragma unroll
  for (int ks = 0; ks < 2; ++ks) {
    short8v sh0 = *(const short8v*)(sm + O_SH + ((wv * 2 + 0) * 16 + r15) * 144 + ks * 64 + quad * 16);
    short8v sh1 = *(const short8v*)(sm + O_SH + ((wv * 2 + 1) * 16 + r15) * 144 + ks * 64 + quad * 16);
    short8v sl0 = *(const short8v*)(sm + O_SL + ((wv * 2 + 0) * 16 + r15) * 144 + ks * 64 + quad * 16);
    short8v sl1 = *(const short8v*)(sm + O_SL + ((wv * 2 + 1) * 16 + r15) * 144 + ks * 64 + quad * 16);
    #pragma unroll
    for (int nt = 0; nt < 2; ++nt) {
      short8v wh = *(const short8v*)(bg0 + 15360 + (nt * 16 + r15) * 144 + ks * 64 + quad * 16);
      short8v wl = *(const short8v*)(bg0 + 19968 + (nt * 16 + r15) * 144 + ks * 64 + quad * 16);
      acc[0][nt] = __builtin_amdgcn_mfma_f32_16x16x32_bf16(sh0, wh, acc[0][nt], 0, 0, 0);
      acc[0][nt] = __builtin_amdgcn_mfma_f32_16x16x32_bf16(sh0, wl, acc[0][nt], 0, 0, 0);
      acc[0][nt] = __builtin_amdgcn_mfma_f32_16x16x32_bf16(sl0, wh, acc[0][nt], 0, 0, 0);
      acc[1][nt] = __builtin_amdgcn_mfma_f32_16x16x32_bf16(sh1, wh, acc[1][nt], 0, 0, 0);
      acc[1][nt] = __builtin_amdgcn_mfma_f32_16x16x32_bf16(sh1, wl, acc[1][nt], 0, 0, 0);
      acc[1][nt] = __builtin_amdgcn_mfma_f32_16x16x32_bf16(sl1, wh, acc[1][nt], 0, 0, 0);
    }
  }

  #pragma unroll
  for (int mt = 0; mt < 2; ++mt)
    #pragma unroll
    for (int nt = 0; nt < 2; ++nt)
      #pragma unroll
      for (int rg = 0; rg < 4; ++rg) {
        int c = (wv * 2 + mt) * 16 + quad * 4 + rg;
        int t = nt * 16 + r15;
        float v = acc[mt][nt][rg];
        v = 0.5f * v * (1.f + erff(v * 0.70710678118654752f));
        *(unsigned short*)(sm + O_U + (c * 32 + t) * 2) = f2bs(v);
      }
  __syncthreads();
  {
    uint4* yo = (uint4*)(y_g + (size_t)bh * L);
    #pragma unroll
    for (int r = 0; r < 2; ++r) {
      int idx = tid + r * 256;
      yo[idx] = *(const uint4*)(sm + O_U + idx * 16);
    }
  }
}

// ------- pointwise conv + GLU + residual + LN v9: zero cross-barrier register state.
// z written to LDS (single bf16) immediately after GLU; LN stats fp32 from pre-rounded z;
// mu/rv computed by tid<64 into P base (self-aliasing, race-free); normalize fused into
// the store phase. LDS 54272 B -> 3 blocks/CU; spill-impossible by construction. -------
__global__ __launch_bounds__(256, 3) void glu_ln9_kernel(
    const unsigned short* __restrict__ y_g, unsigned short* __restrict__ h_g,
    const unsigned short* __restrict__ Wb,  // layer: [hi 256x128] shorts
    const float* __restrict__ ob, const float* __restrict__ lg,
    const float* __restrict__ lb) {
  static __shared__ char __align__(16) sm[54272];
  constexpr int O_Y = 0;        // y transposed [64 pos][136 ch-shorts] = 17408 B (row 272 B)
  constexpr int O_H = 17408;    // h natural  [128 ch][68 pos-shorts]  = 17408 B (row 136 B)
  constexpr int O_Z = 34816;    // z bf16     [128 ch][68 pos-shorts]  = 17408 B (row 136 B)
  constexpr int O_P = 52224;    // LN partials [4 waves][64 pos] float2 = 2048 B
                                // after reduce: P base doubles as mu/rv [64 pos] float2

  int tid = threadIdx.x;
  int wv = tid >> 6, lane = tid & 63, r15 = lane & 15, quad = lane >> 4;
  int b = blockIdx.x >> 4, seg = blockIdx.x & 15;

  // per-lane GLU biases for its channels: ch = (2wv+i)*16 + quad*4 + rg
  float ba[2][4], bgl[2][4];
  #pragma unroll
  for (int i = 0; i < 2; ++i) {
    int ch0 = (2 * wv + i) * 16 + quad * 4;
    #pragma unroll
    for (int rg = 0; rg < 4; ++rg) {
      ba[i][rg]  = ob[ch0 + rg];
      bgl[i][rg] = ob[128 + ch0 + rg];
    }
  }

  for (int t = 0; t < 4; ++t) {
    int l0 = seg * 256 + t * 64;
    // ---- stage y transposed [pos][ch]
    {
      int k = tid >> 1, half = tid & 1;
      const uint4* src = (const uint4*)(y_g + ((size_t)(b * H + k)) * L + l0 + half * 32);
      unsigned short sarr[32];
      uint4* sp = (uint4*)sarr;
      sp[0] = src[0]; sp[1] = src[1]; sp[2] = src[2]; sp[3] = src[3];
      #pragma unroll
      for (int j = 0; j < 32; ++j)
        *(unsigned short*)(sm + O_Y + (half * 32 + j) * 272 + k * 2) = sarr[j];
    }
    // ---- stage h natural [ch][pos]
    {
      #pragma unroll
      for (int i = 0; i < 4; ++i) {
        int id = tid + i * 256;           // 0..1023
        int ch = id >> 3, part = id & 7;
        uint4 v = *(const uint4*)(h_g + ((size_t)(b * H + ch)) * L + l0 + part * 8);
        *(uint4*)(sm + O_H + ch * 136 + part * 16) = v;
      }
    }
    __syncthreads();   // A

    // ---- GEMM + GLU + residual; z -> LDS immediately (no cross-barrier registers)
    float s1[4] = {0.f, 0.f, 0.f, 0.f}, s2[4] = {0.f, 0.f, 0.f, 0.f};
    #pragma unroll
    for (int pt = 0; pt < 4; ++pt) {
      short8v bf[4];
      #pragma unroll
      for (int ks = 0; ks < 4; ++ks)
        bf[ks] = *(const short8v*)(sm + O_Y + (pt * 16 + r15) * 272 + ks * 64 + quad * 16);
      int pos = pt * 16 + r15;
      #pragma unroll
      for (int i = 0; i < 2; ++i) {
        int ch0 = (2 * wv + i) * 16 + quad * 4;
        const unsigned short* wa = Wb + (size_t)((2 * wv + i) * 16 + r15) * 128 + quad * 8;
        floatx4 acca = (floatx4){0.f, 0.f, 0.f, 0.f};
        #pragma unroll
        for (int ks = 0; ks < 4; ++ks) {
          short8v wf = *(const short8v*)(wa + ks * 32);
          acca = __builtin_amdgcn_mfma_f32_16x16x32_bf16(wf, bf[ks], acca, 0, 0, 0);
        }
        const unsigned short* wg = Wb + (size_t)((8 + 2 * wv + i) * 16 + r15) * 128 + quad * 8;
        floatx4 accg = (floatx4){0.f, 0.f, 0.f, 0.f};
        #pragma unroll
        for (int ks = 0; ks < 4; ++ks) {
          short8v wf = *(const short8v*)(wg + ks * 32);
          accg = __builtin_amdgcn_mfma_f32_16x16x32_bf16(wf, bf[ks], accg, 0, 0, 0);
        }
        #pragma unroll
        for (int rg = 0; rg < 4; ++rg) {
          float a = acca[rg] + ba[i][rg];
          float g = accg[rg] + bgl[i][rg];
          float zz = a / (1.f + expf(-g));
          zz += bu2f(*(const unsigned short*)(sm + O_H + (ch0 + rg) * 136 + pos * 2));
          s1[pt] += zz;
          s2[pt] += zz * zz;
          *(unsigned short*)(sm + O_Z + (ch0 + rg) * 136 + pos * 2) = f2bs(zz);
        }
      }
    }
    #pragma unroll
    for (int pt = 0; pt < 4; ++pt) {
      s1[pt] += __shfl_xor(s1[pt], 16, 64); s1[pt] += __shfl_xor(s1[pt], 32, 64);
      s2[pt] += __shfl_xor(s2[pt], 16, 64); s2[pt] += __shfl_xor(s2[pt], 32, 64);
    }
    if (quad == 0) {
      #pragma unroll
      for (int pt = 0; pt < 4; ++pt)
        *(float2*)(sm + O_P + (wv * 64 + pt * 16 + r15) * 8) = make_float2(s1[pt], s2[pt]);
    }
    __syncthreads();   // B (partials + z tile complete)

    // ---- mu/rv by tid<64; write into P base (thread i reads slot i of each wave
    //      BEFORE writing wave-0 slot i, which only thread i reads -> race-free)
    if (tid < 64) {
      float a1 = 0.f, a2 = 0.f;
      #pragma unroll
      for (int w = 0; w < 4; ++w) {
        float2 p = *(const float2*)(sm + O_P + (w * 64 + tid) * 8);
        a1 += p.x; a2 += p.y;
      }
      float m = a1 * (1.f / H);
      float var = a2 * (1.f / H) - m * m;
      if (var < 0.f) var = 0.f;
      *(float2*)(sm + O_P + tid * 8) = make_float2(m, rsqrtf(var + 1e-5f));
    }
    __syncthreads();   // C (mu/rv ready)

    // ---- normalize fused into coalesced store (channel-major)
    {
      int ch = tid >> 1, half = tid & 1;
      float gg = lg[ch], bb2 = lb[ch];
      unsigned outw[16];
      #pragma unroll
      for (int j = 0; j < 32; ++j) {
        float zz = bu2f(*(const unsigned short*)(sm + O_Z + ch * 136 + (half * 32 + j) * 2));
        float2 mr = *(const float2*)(sm + O_P + (half * 32 + j) * 8);
        float v = (zz - mr.x) * mr.y * gg + bb2;
        unsigned short bits = f2bs(v);
        if (j & 1) outw[j >> 1] |= (unsigned)bits << 16;
        else       outw[j >> 1]  = (unsigned)bits;
      }
      uint4* dst = (uint4*)(h_g + ((size_t)(b * H + ch)) * L + l0 + half * 32);
      #pragma unroll
      for (int j = 0; j < 4; ++j)
        dst[j] = *(const uint4*)(&outw[j * 4]);
    }
    // no end barrier: store reads of O_Z/P precede (in each thread) the next tile's
    // barrier A; all other threads' overwrites of Y/H/Z/P happen after A/B -> safe.
  }
}

__global__ __launch_bounds__(256) void pool_kernel(const bf16* __restrict__ h_g,
                                                   float* __restrict__ pooled) {
  int bh = blockIdx.x;
  const bf16* row = h_g + (size_t)bh * L;
  float s = 0.f;
  for (int l = threadIdx.x; l < L; l += 256) s += b2f(row[l]);
  for (int off = 32; off > 0; off >>= 1) s += __shfl_down(s, off);
  __shared__ float wsum[4];
  int lane = threadIdx.x & 63, wv = threadIdx.x >> 6;
  if (lane == 0) wsum[wv] = s;
  __syncthreads();
  if (threadIdx.x == 0)
    pooled[bh] = (wsum[0] + wsum[1] + wsum[2] + wsum[3]) * (1.f / L);
}

__global__ void head_kernel(const float* __restrict__ pooled,
                            const float* __restrict__ head_W,
                            const float* __restrict__ head_b,
                            float* __restrict__ out) {
  int tid = threadIdx.x;
  if (tid >= B * 2) return;
  int b = tid >> 1, o = tid & 1;
  float acc = head_b[o];
  for (int ch = 0; ch < H; ++ch)
    acc += pooled[b * H + ch] * head_W[ch * 2 + o];
  out[tid] = acc;
}

extern "C" void kernel_launch(void* const* d_in, const int* in_sizes, int n_in,
                              void* d_out, int out_size, void* d_ws, size_t ws_size,
                              hipStream_t stream) {
  const float* x          = (const float*)d_in[0];
  const float* enc_W      = (const float*)d_in[1];
  const float* enc_b      = (const float*)d_in[2];
  const float* log_dt     = (const float*)d_in[3];
  const float* C_re       = (const float*)d_in[4];
  const float* C_im       = (const float*)d_in[5];
  const float* log_A_real = (const float*)d_in[6];
  const float* A_imag     = (const float*)d_in[7];
  const float* Dp         = (const float*)d_in[8];
  const float* out_W      = (const float*)d_in[9];
  const float* out_b      = (const float*)d_in[10];
  const float* ln_g       = (const float*)d_in[11];
  const float* ln_b       = (const float*)d_in[12];
  const float* head_W     = (const float*)d_in[13];
  const float* head_b     = (const float*)d_in[14];

  // ws: hbuf bf16 32MB | ybuf bf16 32MB | Wb bf16 hi/lo 1.5MB | pooled | Bg 3MB | wTg
  bf16* hbuf = (bf16*)d_ws;
  bf16* ybuf = hbuf + (size_t)B * H * L;
  unsigned short* Wb = (unsigned short*)(ybuf + (size_t)B * H * L);
  float* pooled = (float*)(Wb + (size_t)NL * 65536);
  unsigned short* Bg = (unsigned short*)(pooled + B * H);
  float2* wTg = (float2*)(Bg + (size_t)12288 * H);

  encoder_kernel<<<B * H, 256, 0, stream>>>(x, enc_W, enc_b, hbuf);
  w_prep_kernel<<<(NL * 2 * H * H + 255) / 256, 256, 0, stream>>>(out_W, Wb);

  for (int layer = 0; layer < NL; ++layer) {
    s4d_prep_kernel<<<H, 256, 0, stream>>>(log_dt, C_re, C_im, log_A_real,
                                           A_imag, Dp, Bg, wTg, layer);
    s4d_conv4_kernel<<<B * H, 256, 0, stream>>>(hbuf, ybuf, Bg, wTg);
    glu_ln9_kernel<<<B * 16, 256, 0, stream>>>(
        (const unsigned short*)ybuf, (unsigned short*)hbuf,
        Wb + (size_t)layer * 65536, out_b + layer * 2 * H,
        ln_g + layer * H, ln_b + layer * H);
  }

  pool_kernel<<<B * H, 256, 0, stream>>>(hbuf, pooled);
  head_kernel<<<1, 64, 0, stream>>>(pooled, head_W, head_b, (float*)d_out);
}

// Round 15
// 717.256 us; speedup vs baseline: 1.3884x; 1.2439x over previous
//
#include <hip/hip_runtime.h>
#include <hip/hip_bf16.h>

#define B 32
#define H 128
#define L 4096
#define NC 32
#define NL 6
#define NCHUNK 128

typedef __hip_bfloat16 bf16;
typedef __attribute__((ext_vector_type(8))) short short8v;   // 8 bf16 (4 VGPR)
typedef __attribute__((ext_vector_type(4))) float floatx4;   // MFMA C/D

__device__ __forceinline__ float b2f(bf16 v) { return __bfloat162float(v); }
__device__ __forceinline__ float bu2f(unsigned int u) {
  union { unsigned int i; float f; } v; v.i = u << 16; return v.f;
}
// float -> bf16 bits, round-to-nearest-even
__device__ __forceinline__ unsigned short f2bs(float f) {
  unsigned u = __float_as_uint(f);
  u = (u + 0x7fffu + ((u >> 16) & 1u)) >> 16;
  return (unsigned short)u;
}

// ---------------- encoder ----------------
__global__ void encoder_kernel(const float* __restrict__ x, const float* __restrict__ enc_W,
                               const float* __restrict__ enc_b, bf16* __restrict__ h) {
  int blk = blockIdx.x;
  int b = blk >> 7, ch = blk & 127;
  float w0 = enc_W[ch];
  float w1 = enc_W[H + ch];
  float bb = enc_b[ch];
  const float* x0 = x + (size_t)b * 2 * L;
  const float* x1 = x0 + L;
  bf16* out = h + ((size_t)b * H + ch) * L;
  for (int l = threadIdx.x; l < L; l += blockDim.x)
    out[l] = __float2bfloat16(x0[l] * w0 + x1[l] * w1 + bb);
}

// Wb[l][hl][o][k]: hi/lo bf16 split of out_W[l][o][k]; per-layer stride 65536
// (glu uses only the hi plane)
__global__ void w_prep_kernel(const float* __restrict__ out_W, unsigned short* __restrict__ Wb) {
  int idx = blockIdx.x * 256 + threadIdx.x;
  if (idx >= NL * 2 * H * H) return;
  int l = idx / (2 * H * H);
  int rem = idx % (2 * H * H);
  float v = out_W[idx];
  unsigned short hi = f2bs(v);
  unsigned short lo = f2bs(v - bu2f(hi));
  Wb[(size_t)l * 65536 + rem] = hi;
  Wb[(size_t)l * 65536 + 32768 + rem] = lo;
}

// ---------------- per-(layer,h) B-matrix precompute ----------------
__global__ __launch_bounds__(256) void s4d_prep_kernel(
    const float* __restrict__ log_dt, const float* __restrict__ C_re,
    const float* __restrict__ C_im, const float* __restrict__ log_A_real,
    const float* __restrict__ A_imag, const float* __restrict__ Dp,
    unsigned short* __restrict__ Bg, float2* __restrict__ wTg, int layer) {
  __shared__ float2 dta_s[NC], cd_s[NC];
  __shared__ float K_s[32];
  int h = blockIdx.x, tid = threadIdx.x;
  if (tid < NC) {
    int n = tid, base = (layer * H + h) * NC + n;
    float dt = expf(log_dt[layer * H + h]);
    float Are = -expf(log_A_real[base]);
    float Aim = A_imag[base];
    float dre = dt * Are, dim = dt * Aim;
    float er = expf(dre);
    float wre = er * cosf(dim), wim = er * sinf(dim);
    float emre = wre - 1.f, emim = wim;   // expm1(dtA)
    float cre = C_re[base], cim = C_im[base];
    float nre = cre * emre - cim * emim, nim = cre * emim + cim * emre;
    float den = Are * Are + Aim * Aim;
    dta_s[n] = make_float2(dre, dim);
    cd_s[n] = make_float2((nre * Are + nim * Aim) / den, (nim * Are - nre * Aim) / den);
    float e32 = expf(dre * 32.f);
    wTg[h * NC + n] = make_float2(e32 * cosf(dim * 32.f), e32 * sinf(dim * 32.f));
  }
  __syncthreads();
  if (tid < 32) {  // K[tau] = 2 sum_n Re(cd_n w_n^tau)
    float acc = 0.f;
    float tau = (float)tid;
    for (int n = 0; n < NC; ++n) {
      float e = expf(dta_s[n].x * tau);
      float pr = e * cosf(dta_s[n].y * tau), pi = e * sinf(dta_s[n].y * tau);
      acc += cd_s[n].x * pr - cd_s[n].y * pi;
    }
    K_s[tid] = 2.f * acc;
  }
  __syncthreads();
  unsigned short* bb = Bg + (size_t)h * 12288;
  float Dv = Dp[layer * H + h];
  #pragma unroll
  for (int i = 0; i < 8; ++i) {     // VT: 2048 entries
    int idx = tid + i * 256;
    int n2 = idx >> 5, t = idx & 31, n = n2 >> 1;
    float k = (float)(31 - t);
    float e = expf(dta_s[n].x * k);
    float v = (n2 & 1) ? e * sinf(dta_s[n].y * k) : e * cosf(dta_s[n].y * k);
    unsigned short hi = f2bs(v);
    unsigned short lo = f2bs(v - bu2f(hi));
    bb[n2 * 40 + t] = hi;
    bb[2560 + n2 * 40 + t] = lo;
  }
  #pragma unroll
  for (int i = 0; i < 4; ++i) {     // KT: 1024 entries
    int idx = tid + i * 256;
    int t = idx >> 5, m = idx & 31;
    float v = (m > t) ? 0.f : (K_s[t - m] + (m == t ? Dv : 0.f));
    unsigned short hi = f2bs(v);
    unsigned short lo = f2bs(v - bu2f(hi));
    bb[5120 + t * 40 + m] = hi;
    bb[6400 + t * 40 + m] = lo;
  }
  #pragma unroll
  for (int i = 0; i < 8; ++i) {     // WT: 2048 entries
    int idx = tid + i * 256;
    int t = idx >> 6, k = idx & 63, n = k >> 1;
    float tp = (float)(t + 1);
    float e = expf(dta_s[n].x * tp);
    float pr = e * cosf(dta_s[n].y * tp), pi = e * sinf(dta_s[n].y * tp);
    float cwr = cd_s[n].x * pr - cd_s[n].y * pi;
    float cwi = cd_s[n].x * pi + cd_s[n].y * pr;
    float v = (k & 1) ? -2.f * cwi : 2.f * cwr;
    unsigned short hi = f2bs(v);
    unsigned short lo = f2bs(v - bu2f(hi));
    bb[7680 + t * 72 + k] = hi;
    bb[9984 + t * 72 + k] = lo;
  }
}

// ---------------- S4D conv v4: B-frags direct from L2, 51.5 KB LDS -> 3 blocks/CU (R11, proven) ----------------
__global__ __launch_bounds__(256, 3) void s4d_conv4_kernel(
    const bf16* __restrict__ u_g, bf16* __restrict__ y_g,
    const unsigned short* __restrict__ Bg, const float2* __restrict__ wTg) {
  static __shared__ char __align__(16) sm[51456];
  constexpr int O_U = 0;
  constexpr int O_SH = 10240;
  constexpr int O_SL = 28672;
  constexpr int O_WT = 47104;
  constexpr int O_GE = 47360;
  constexpr int O_GT = 49408;

  int tid = threadIdx.x;
  int lane = tid & 63, wv = tid >> 6;
  int r15 = lane & 15, quad = lane >> 4;
  int bh = blockIdx.x, hh = bh & 127;
  const char* bg0 = (const char*)(Bg + (size_t)hh * 12288);

  {
    const uint4* ug = (const uint4*)(u_g + (size_t)bh * L);
    #pragma unroll
    for (int r = 0; r < 2; ++r) {
      int idx = tid + r * 256;
      *(uint4*)(sm + O_U + (idx >> 2) * 80 + (idx & 3) * 16) = ug[idx];
    }
  }
  if (tid < 32) *(float2*)(sm + O_WT + tid * 8) = wTg[hh * 32 + tid];

  short8v bvh[4], bvl[4];
  #pragma unroll
  for (int nt = 0; nt < 4; ++nt) {
    bvh[nt] = *(const short8v*)(bg0 + 0    + (nt * 16 + r15) * 80 + quad * 16);
    bvl[nt] = *(const short8v*)(bg0 + 5120 + (nt * 16 + r15) * 80 + quad * 16);
  }
  __syncthreads();

  short8v aU0 = *(const short8v*)(sm + O_U + ((wv * 2 + 0) * 16 + r15) * 80 + quad * 16);
  short8v aU1 = *(const short8v*)(sm + O_U + ((wv * 2 + 1) * 16 + r15) * 80 + quad * 16);
  floatx4 cp[2][4];
  #pragma unroll
  for (int mt = 0; mt < 2; ++mt)
    #pragma unroll
    for (int nt = 0; nt < 4; ++nt) cp[mt][nt] = (floatx4){0.f, 0.f, 0.f, 0.f};
  #pragma unroll
  for (int nt = 0; nt < 4; ++nt) {
    cp[0][nt] = __builtin_amdgcn_mfma_f32_16x16x32_bf16(aU0, bvh[nt], cp[0][nt], 0, 0, 0);
    cp[0][nt] = __builtin_amdgcn_mfma_f32_16x16x32_bf16(aU0, bvl[nt], cp[0][nt], 0, 0, 0);
    cp[1][nt] = __builtin_amdgcn_mfma_f32_16x16x32_bf16(aU1, bvh[nt], cp[1][nt], 0, 0, 0);
    cp[1][nt] = __builtin_amdgcn_mfma_f32_16x16x32_bf16(aU1, bvl[nt], cp[1][nt], 0, 0, 0);
  }
  #pragma unroll
  for (int mt = 0; mt < 2; ++mt)
    #pragma unroll
    for (int nt = 0; nt < 4; ++nt) {
      int n2 = nt * 16 + r15;
      int off = ((n2 & 1) ? O_SL : O_SH) + (n2 >> 1) * 4;
      #pragma unroll
      for (int rg = 0; rg < 4; ++rg) {
        int c = (wv * 2 + mt) * 16 + quad * 4 + rg;
        *(float*)(sm + off + c * 144) = cp[mt][nt][rg];
      }
    }
  __syncthreads();

  {
    int g = tid >> 5, n = tid & 31;
    float2 wt = *(const float2*)(sm + O_WT + n * 8);
    float rr = 0.f, ri = 0.f;
    for (int k = 0; k < 16; ++k) {
      int c = g * 16 + k;
      float* pr = (float*)(sm + O_SH + c * 144 + n * 4);
      float* pi = (float*)(sm + O_SL + c * 144 + n * 4);
      float pre_ = *pr, pim_ = *pi;
      *pr = rr; *pi = ri;
      float nr = wt.x * rr - wt.y * ri + pre_;
      ri = wt.x * ri + wt.y * rr + pim_;
      rr = nr;
    }
    *(float2*)(sm + O_GT + (g * 32 + n) * 8) = make_float2(rr, ri);
  }
  __syncthreads();
  if (tid < 32) {
    float2 wt = *(const float2*)(sm + O_WT + tid * 8);
    float w2r = wt.x * wt.x - wt.y * wt.y,   w2i = 2.f * wt.x * wt.y;
    float w4r = w2r * w2r - w2i * w2i,       w4i = 2.f * w2r * w2i;
    float w8r = w4r * w4r - w4i * w4i,       w8i = 2.f * w4r * w4i;
    float w16r = w8r * w8r - w8i * w8i,      w16i = 2.f * w8r * w8i;
    float rr = 0.f, ri = 0.f;
    for (int g = 0; g < 8; ++g) {
      *(float2*)(sm + O_GE + (g * 32 + tid) * 8) = make_float2(rr, ri);
      float2 gt = *(const float2*)(sm + O_GT + (g * 32 + tid) * 8);
      float nr = w16r * rr - w16i * ri + gt.x;
      ri = w16r * ri + w16i * rr + gt.y;
      rr = nr;
    }
  }
  __syncthreads();
  {
    int g = tid >> 5, n = tid & 31;
    float2 wt = *(const float2*)(sm + O_WT + n * 8);
    float2 ge = *(const float2*)(sm + O_GE + (g * 32 + n) * 8);
    float ar = ge.x, ai = ge.y;
    for (int k = 0; k < 16; ++k) {
      int c = g * 16 + k;
      char* ph = sm + O_SH + c * 144 + n * 4;
      char* pl = sm + O_SL + c * 144 + n * 4;
      float er = *(const float*)ph + ar;
      float ei = *(const float*)pl + ai;
      unsigned short hr = f2bs(er), him = f2bs(ei);
      *(unsigned*)ph = ((unsigned)him << 16) | hr;
      *(unsigned*)pl = ((unsigned)f2bs(ei - bu2f(him)) << 16) | f2bs(er - bu2f(hr));
      float nr = ar * wt.x - ai * wt.y;
      ai = ar * wt.y + ai * wt.x;
      ar = nr;
    }
  }
  __syncthreads();

  floatx4 acc[2][2];
  #pragma unroll
  for (int mt = 0; mt < 2; ++mt)
    #pragma unroll
    for (int nt = 0; nt < 2; ++nt) acc[mt][nt] = (floatx4){0.f, 0.f, 0.f, 0.f};
  #pragma unroll
  for (int nt = 0; nt < 2; ++nt) {
    short8v kh = *(const short8v*)(bg0 + 10240 + (nt * 16 + r15) * 80 + quad * 16);
    short8v kl = *(const short8v*)(bg0 + 12800 + (nt * 16 + r15) * 80 + quad * 16);
    acc[0][nt] = __builtin_amdgcn_mfma_f32_16x16x32_bf16(aU0, kh, acc[0][nt], 0, 0, 0);
    acc[0][nt] = __builtin_amdgcn_mfma_f32_16x16x32_bf16(aU0, kl, acc[0][nt], 0, 0, 0);
    acc[1][nt] = __builtin_amdgcn_mfma_f32_16x16x32_bf16(aU1, kh, acc[1][nt], 0, 0, 0);
    acc[1][nt] = __builtin_amdgcn_mfma_f32_16x16x32_bf16(aU1, kl, acc[1][nt], 0, 0, 0);
  }
  #pragma unroll
  for (int ks = 0; ks < 2; ++ks) {
    short8v sh0 = *(const short8v*)(sm + O_SH + ((wv * 2 + 0) * 16 + r15) * 144 + ks * 64 + quad * 16);
    short8v sh1 = *(const short8v*)(sm + O_SH + ((wv * 2 + 1) * 16 + r15) * 144 + ks * 64 + quad * 16);
    short8v sl0 = *(const short8v*)(sm + O_SL + ((wv * 2 + 0) * 16 + r15) * 144 + ks * 64 + quad * 16);
    short8v sl1 = *(const short8v*)(sm + O_SL + ((wv * 2 + 1) * 16 + r15) * 144 + ks * 64 + quad * 16);
    #pragma unroll
    for (int nt = 0; nt < 2; ++nt) {
      short8v wh = *(const short8v*)(bg0 + 15360 + (nt * 16 + r15) * 144 + ks * 64 + quad * 16);
      short8v wl = *(const short8v*)(bg0 + 19968 + (nt * 16 + r15) * 144 + ks * 64 + quad * 16);
      acc[0][nt] = __builtin_amdgcn_mfma_f32_16x16x32_bf16(sh0, wh, acc[0][nt], 0, 0, 0);
      acc[0][nt] = __builtin_amdgcn_mfma_f32_16x16x32_bf16(sh0, wl, acc[0][nt], 0, 0, 0);
      acc[0][nt] = __builtin_amdgcn_mfma_f32_16x16x32_bf16(sl0, wh, acc[0][nt], 0, 0, 0);
      acc[1][nt] = __builtin_amdgcn_mfma_f32_16x16x32_bf16(sh1, wh, acc[1][nt], 0, 0, 0);
      acc[1][nt] = __builtin_amdgcn_mfma_f32_16x16x32_bf16(sh1, wl, acc[1][nt], 0, 0, 0);
      acc[1][nt] = __builtin_amdgcn_mfma_f32_16x16x32_bf16(sl1, wh, acc[1][nt], 0, 0, 0);
    }
  }

  #pragma unroll
  for (int mt = 0; mt < 2; ++mt)
    #pragma unroll
    for (int nt = 0; nt < 2; ++nt)
      #pragma unroll
      for (int rg = 0; rg < 4; ++rg) {
        int c = (wv * 2 + mt) * 16 + quad * 4 + rg;
        int t = nt * 16 + r15;
        float v = acc[mt][nt][rg];
        v = 0.5f * v * (1.f + erff(v * 0.70710678118654752f));
        *(unsigned short*)(sm + O_U + (c * 32 + t) * 2) = f2bs(v);
      }
  __syncthreads();
  {
    uint4* yo = (uint4*)(y_g + (size_t)bh * L);
    #pragma unroll
    for (int r = 0; r < 2; ++r) {
      int idx = tid + r * 256;
      yo[idx] = *(const uint4*)(sm + O_U + idx * 16);
    }
  }
}

// ------- pointwise conv + GLU + residual + LN v10: ln9 structure at waves=2 (spill-free),
// z tile ALIASES h tile in-place (each (ch,pos) slot: read-h-then-write-z by its unique
// owner lane -> race-free), LDS 36864 B -> up to 4 blocks/CU. 4 barriers/tile. -------
__global__ __launch_bounds__(256, 2) void glu_ln10_kernel(
    const unsigned short* __restrict__ y_g, unsigned short* __restrict__ h_g,
    const unsigned short* __restrict__ Wb,  // layer: [hi 256x128] shorts
    const float* __restrict__ ob, const float* __restrict__ lg,
    const float* __restrict__ lb) {
  static __shared__ char __align__(16) sm[36864];
  constexpr int O_Y = 0;        // y transposed [64 pos][136 ch-shorts] = 17408 B (row 272 B)
  constexpr int O_H = 17408;    // h natural [128 ch][68 pos-shorts] = 17408 B; z aliases in-place
  constexpr int O_P = 34816;    // LN partials [4 waves][64 pos] float2 = 2048 B
                                // after reduce: P base doubles as mu/rv [64 pos] float2

  int tid = threadIdx.x;
  int wv = tid >> 6, lane = tid & 63, r15 = lane & 15, quad = lane >> 4;
  int b = blockIdx.x >> 4, seg = blockIdx.x & 15;

  // per-lane GLU biases for its channels: ch = (2wv+i)*16 + quad*4 + rg
  float ba[2][4], bgl[2][4];
  #pragma unroll
  for (int i = 0; i < 2; ++i) {
    int ch0 = (2 * wv + i) * 16 + quad * 4;
    #pragma unroll
    for (int rg = 0; rg < 4; ++rg) {
      ba[i][rg]  = ob[ch0 + rg];
      bgl[i][rg] = ob[128 + ch0 + rg];
    }
  }

  for (int t = 0; t < 4; ++t) {
    int l0 = seg * 256 + t * 64;
    // ---- stage y transposed [pos][ch]
    {
      int k = tid >> 1, half = tid & 1;
      const uint4* src = (const uint4*)(y_g + ((size_t)(b * H + k)) * L + l0 + half * 32);
      unsigned short sarr[32];
      uint4* sp = (uint4*)sarr;
      sp[0] = src[0]; sp[1] = src[1]; sp[2] = src[2]; sp[3] = src[3];
      #pragma unroll
      for (int j = 0; j < 32; ++j)
        *(unsigned short*)(sm + O_Y + (half * 32 + j) * 272 + k * 2) = sarr[j];
    }
    // ---- stage h natural [ch][pos]
    {
      #pragma unroll
      for (int i = 0; i < 4; ++i) {
        int id = tid + i * 256;           // 0..1023
        int ch = id >> 3, part = id & 7;
        uint4 v = *(const uint4*)(h_g + ((size_t)(b * H + ch)) * L + l0 + part * 8);
        *(uint4*)(sm + O_H + ch * 136 + part * 16) = v;
      }
    }
    __syncthreads();   // A

    // ---- GEMM + GLU + residual; z overwrites h slot in-place (unique owner lane)
    float s1[4] = {0.f, 0.f, 0.f, 0.f}, s2[4] = {0.f, 0.f, 0.f, 0.f};
    #pragma unroll
    for (int pt = 0; pt < 4; ++pt) {
      short8v bf[4];
      #pragma unroll
      for (int ks = 0; ks < 4; ++ks)
        bf[ks] = *(const short8v*)(sm + O_Y + (pt * 16 + r15) * 272 + ks * 64 + quad * 16);
      int pos = pt * 16 + r15;
      #pragma unroll
      for (int i = 0; i < 2; ++i) {
        int ch0 = (2 * wv + i) * 16 + quad * 4;
        const unsigned short* wa = Wb + (size_t)((2 * wv + i) * 16 + r15) * 128 + quad * 8;
        floatx4 acca = (floatx4){0.f, 0.f, 0.f, 0.f};
        #pragma unroll
        for (int ks = 0; ks < 4; ++ks) {
          short8v wf = *(const short8v*)(wa + ks * 32);
          acca = __builtin_amdgcn_mfma_f32_16x16x32_bf16(wf, bf[ks], acca, 0, 0, 0);
        }
        const unsigned short* wg = Wb + (size_t)((8 + 2 * wv + i) * 16 + r15) * 128 + quad * 8;
        floatx4 accg = (floatx4){0.f, 0.f, 0.f, 0.f};
        #pragma unroll
        for (int ks = 0; ks < 4; ++ks) {
          short8v wf = *(const short8v*)(wg + ks * 32);
          accg = __builtin_amdgcn_mfma_f32_16x16x32_bf16(wf, bf[ks], accg, 0, 0, 0);
        }
        #pragma unroll
        for (int rg = 0; rg < 4; ++rg) {
          float a = acca[rg] + ba[i][rg];
          float g = accg[rg] + bgl[i][rg];
          float zz = a / (1.f + expf(-g));
          char* slot = sm + O_H + (ch0 + rg) * 136 + pos * 2;
          zz += bu2f(*(const unsigned short*)slot);   // residual read
          s1[pt] += zz;
          s2[pt] += zz * zz;
          *(unsigned short*)slot = f2bs(zz);          // z write, same slot, same lane
        }
      }
    }
    #pragma unroll
    for (int pt = 0; pt < 4; ++pt) {
      s1[pt] += __shfl_xor(s1[pt], 16, 64); s1[pt] += __shfl_xor(s1[pt], 32, 64);
      s2[pt] += __shfl_xor(s2[pt], 16, 64); s2[pt] += __shfl_xor(s2[pt], 32, 64);
    }
    if (quad == 0) {
      #pragma unroll
      for (int pt = 0; pt < 4; ++pt)
        *(float2*)(sm + O_P + (wv * 64 + pt * 16 + r15) * 8) = make_float2(s1[pt], s2[pt]);
    }
    __syncthreads();   // B (partials + z tile complete)

    // ---- mu/rv by tid<64 into P base (reads all wave slots before writing slot tid,
    //      which only thread tid reads afterwards -> race-free)
    if (tid < 64) {
      float a1 = 0.f, a2 = 0.f;
      #pragma unroll
      for (int w = 0; w < 4; ++w) {
        float2 p = *(const float2*)(sm + O_P + (w * 64 + tid) * 8);
        a1 += p.x; a2 += p.y;
      }
      float m = a1 * (1.f / H);
      float var = a2 * (1.f / H) - m * m;
      if (var < 0.f) var = 0.f;
      *(float2*)(sm + O_P + tid * 8) = make_float2(m, rsqrtf(var + 1e-5f));
    }
    __syncthreads();   // C (mu/rv ready)

    // ---- normalize fused into coalesced store (channel-major)
    {
      int ch = tid >> 1, half = tid & 1;
      float gg = lg[ch], bb2 = lb[ch];
      unsigned outw[16];
      #pragma unroll
      for (int j = 0; j < 32; ++j) {
        float zz = bu2f(*(const unsigned short*)(sm + O_H + ch * 136 + (half * 32 + j) * 2));
        float2 mr = *(const float2*)(sm + O_P + (half * 32 + j) * 8);
        float v = (zz - mr.x) * mr.y * gg + bb2;
        unsigned short bits = f2bs(v);
        if (j & 1) outw[j >> 1] |= (unsigned)bits << 16;
        else       outw[j >> 1]  = (unsigned)bits;
      }
      uint4* dst = (uint4*)(h_g + ((size_t)(b * H + ch)) * L + l0 + half * 32);
      #pragma unroll
      for (int j = 0; j < 4; ++j)
        dst[j] = *(const uint4*)(&outw[j * 4]);
    }
    __syncthreads();   // D: store reads of O_H/P complete before next tile's staging writes
  }
}

__global__ __launch_bounds__(256) void pool_kernel(const bf16* __restrict__ h_g,
                                                   float* __restrict__ pooled) {
  int bh = blockIdx.x;
  const bf16* row = h_g + (size_t)bh * L;
  float s = 0.f;
  for (int l = threadIdx.x; l < L; l += 256) s += b2f(row[l]);
  for (int off = 32; off > 0; off >>= 1) s += __shfl_down(s, off);
  __shared__ float wsum[4];
  int lane = threadIdx.x & 63, wv = threadIdx.x >> 6;
  if (lane == 0) wsum[wv] = s;
  __syncthreads();
  if (threadIdx.x == 0)
    pooled[bh] = (wsum[0] + wsum[1] + wsum[2] + wsum[3]) * (1.f / L);
}

__global__ void head_kernel(const float* __restrict__ pooled,
                            const float* __restrict__ head_W,
                            const float* __restrict__ head_b,
                            float* __restrict__ out) {
  int tid = threadIdx.x;
  if (tid >= B * 2) return;
  int b = tid >> 1, o = tid & 1;
  float acc = head_b[o];
  for (int ch = 0; ch < H; ++ch)
    acc += pooled[b * H + ch] * head_W[ch * 2 + o];
  out[tid] = acc;
}

extern "C" void kernel_launch(void* const* d_in, const int* in_sizes, int n_in,
                              void* d_out, int out_size, void* d_ws, size_t ws_size,
                              hipStream_t stream) {
  const float* x          = (const float*)d_in[0];
  const float* enc_W      = (const float*)d_in[1];
  const float* enc_b      = (const float*)d_in[2];
  const float* log_dt     = (const float*)d_in[3];
  const float* C_re       = (const float*)d_in[4];
  const float* C_im       = (const float*)d_in[5];
  const float* log_A_real = (const float*)d_in[6];
  const float* A_imag     = (const float*)d_in[7];
  const float* Dp         = (const float*)d_in[8];
  const float* out_W      = (const float*)d_in[9];
  const float* out_b      = (const float*)d_in[10];
  const float* ln_g       = (const float*)d_in[11];
  const float* ln_b       = (const float*)d_in[12];
  const float* head_W     = (const float*)d_in[13];
  const float* head_b     = (const float*)d_in[14];

  // ws: hbuf bf16 32MB | ybuf bf16 32MB | Wb bf16 hi/lo 1.5MB | pooled | Bg 3MB | wTg
  bf16* hbuf = (bf16*)d_ws;
  bf16* ybuf = hbuf + (size_t)B * H * L;
  unsigned short* Wb = (unsigned short*)(ybuf + (size_t)B * H * L);
  float* pooled = (float*)(Wb + (size_t)NL * 65536);
  unsigned short* Bg = (unsigned short*)(pooled + B * H);
  float2* wTg = (float2*)(Bg + (size_t)12288 * H);

  encoder_kernel<<<B * H, 256, 0, stream>>>(x, enc_W, enc_b, hbuf);
  w_prep_kernel<<<(NL * 2 * H * H + 255) / 256, 256, 0, stream>>>(out_W, Wb);

  for (int layer = 0; layer < NL; ++layer) {
    s4d_prep_kernel<<<H, 256, 0, stream>>>(log_dt, C_re, C_im, log_A_real,
                                           A_imag, Dp, Bg, wTg, layer);
    s4d_conv4_kernel<<<B * H, 256, 0, stream>>>(hbuf, ybuf, Bg, wTg);
    glu_ln10_kernel<<<B * 16, 256, 0, stream>>>(
        (const unsigned short*)ybuf, (unsigned short*)hbuf,
        Wb + (size_t)layer * 65536, out_b + layer * 2 * H,
        ln_g + layer * H, ln_b + layer * H);
  }

  pool_kernel<<<B * H, 256, 0, stream>>>(hbuf, pooled);
  head_kernel<<<1, 64, 0, stream>>>(pooled, head_W, head_b, (float*)d_out);
}

// Round 16
// 703.245 us; speedup vs baseline: 1.4161x; 1.0199x over previous
//
#include <hip/hip_runtime.h>
#include <hip/hip_bf16.h>

#define B 32
#define H 128
#define L 4096
#define NC 32
#define NL 6
#define NCHUNK 128

typedef __hip_bfloat16 bf16;
typedef __attribute__((ext_vector_type(8))) short short8v;   // 8 bf16 (4 VGPR)
typedef __attribute__((ext_vector_type(4))) float floatx4;   // MFMA C/D

__device__ __forceinline__ float b2f(bf16 v) { return __bfloat162float(v); }
__device__ __forceinline__ float bu2f(unsigned int u) {
  union { unsigned int i; float f; } v; v.i = u << 16; return v.f;
}
// float -> bf16 bits, round-to-nearest-even
__device__ __forceinline__ unsigned short f2bs(float f) {
  unsigned u = __float_as_uint(f);
  u = (u + 0x7fffu + ((u >> 16) & 1u)) >> 16;
  return (unsigned short)u;
}

// ---------------- encoder ----------------
__global__ void encoder_kernel(const float* __restrict__ x, const float* __restrict__ enc_W,
                               const float* __restrict__ enc_b, bf16* __restrict__ h) {
  int blk = blockIdx.x;
  int b = blk >> 7, ch = blk & 127;
  float w0 = enc_W[ch];
  float w1 = enc_W[H + ch];
  float bb = enc_b[ch];
  const float* x0 = x + (size_t)b * 2 * L;
  const float* x1 = x0 + L;
  bf16* out = h + ((size_t)b * H + ch) * L;
  for (int l = threadIdx.x; l < L; l += blockDim.x)
    out[l] = __float2bfloat16(x0[l] * w0 + x1[l] * w1 + bb);
}

// Wb[l][hl][o][k]: hi/lo bf16 split of out_W[l][o][k]; per-layer stride 65536
// (glu uses only the hi plane)
__global__ void w_prep_kernel(const float* __restrict__ out_W, unsigned short* __restrict__ Wb) {
  int idx = blockIdx.x * 256 + threadIdx.x;
  if (idx >= NL * 2 * H * H) return;
  int l = idx / (2 * H * H);
  int rem = idx % (2 * H * H);
  float v = out_W[idx];
  unsigned short hi = f2bs(v);
  unsigned short lo = f2bs(v - bu2f(hi));
  Wb[(size_t)l * 65536 + rem] = hi;
  Wb[(size_t)l * 65536 + 32768 + rem] = lo;
}

// ---------------- per-(layer,h) B-matrix precompute ----------------
__global__ __launch_bounds__(256) void s4d_prep_kernel(
    const float* __restrict__ log_dt, const float* __restrict__ C_re,
    const float* __restrict__ C_im, const float* __restrict__ log_A_real,
    const float* __restrict__ A_imag, const float* __restrict__ Dp,
    unsigned short* __restrict__ Bg, float2* __restrict__ wTg, int layer) {
  __shared__ float2 dta_s[NC], cd_s[NC];
  __shared__ float K_s[32];
  int h = blockIdx.x, tid = threadIdx.x;
  if (tid < NC) {
    int n = tid, base = (layer * H + h) * NC + n;
    float dt = expf(log_dt[layer * H + h]);
    float Are = -expf(log_A_real[base]);
    float Aim = A_imag[base];
    float dre = dt * Are, dim = dt * Aim;
    float er = expf(dre);
    float wre = er * cosf(dim), wim = er * sinf(dim);
    float emre = wre - 1.f, emim = wim;   // expm1(dtA)
    float cre = C_re[base], cim = C_im[base];
    float nre = cre * emre - cim * emim, nim = cre * emim + cim * emre;
    float den = Are * Are + Aim * Aim;
    dta_s[n] = make_float2(dre, dim);
    cd_s[n] = make_float2((nre * Are + nim * Aim) / den, (nim * Are - nre * Aim) / den);
    float e32 = expf(dre * 32.f);
    wTg[h * NC + n] = make_float2(e32 * cosf(dim * 32.f), e32 * sinf(dim * 32.f));
  }
  __syncthreads();
  if (tid < 32) {  // K[tau] = 2 sum_n Re(cd_n w_n^tau)
    float acc = 0.f;
    float tau = (float)tid;
    for (int n = 0; n < NC; ++n) {
      float e = expf(dta_s[n].x * tau);
      float pr = e * cosf(dta_s[n].y * tau), pi = e * sinf(dta_s[n].y * tau);
      acc += cd_s[n].x * pr - cd_s[n].y * pi;
    }
    K_s[tid] = 2.f * acc;
  }
  __syncthreads();
  unsigned short* bb = Bg + (size_t)h * 12288;
  float Dv = Dp[layer * H + h];
  #pragma unroll
  for (int i = 0; i < 8; ++i) {     // VT: 2048 entries
    int idx = tid + i * 256;
    int n2 = idx >> 5, t = idx & 31, n = n2 >> 1;
    float k = (float)(31 - t);
    float e = expf(dta_s[n].x * k);
    float v = (n2 & 1) ? e * sinf(dta_s[n].y * k) : e * cosf(dta_s[n].y * k);
    unsigned short hi = f2bs(v);
    unsigned short lo = f2bs(v - bu2f(hi));
    bb[n2 * 40 + t] = hi;
    bb[2560 + n2 * 40 + t] = lo;
  }
  #pragma unroll
  for (int i = 0; i < 4; ++i) {     // KT: 1024 entries
    int idx = tid + i * 256;
    int t = idx >> 5, m = idx & 31;
    float v = (m > t) ? 0.f : (K_s[t - m] + (m == t ? Dv : 0.f));
    unsigned short hi = f2bs(v);
    unsigned short lo = f2bs(v - bu2f(hi));
    bb[5120 + t * 40 + m] = hi;
    bb[6400 + t * 40 + m] = lo;
  }
  #pragma unroll
  for (int i = 0; i < 8; ++i) {     // WT: 2048 entries
    int idx = tid + i * 256;
    int t = idx >> 6, k = idx & 63, n = k >> 1;
    float tp = (float)(t + 1);
    float e = expf(dta_s[n].x * tp);
    float pr = e * cosf(dta_s[n].y * tp), pi = e * sinf(dta_s[n].y * tp);
    float cwr = cd_s[n].x * pr - cd_s[n].y * pi;
    float cwi = cd_s[n].x * pi + cd_s[n].y * pr;
    float v = (k & 1) ? -2.f * cwi : 2.f * cwr;
    unsigned short hi = f2bs(v);
    unsigned short lo = f2bs(v - bu2f(hi));
    bb[7680 + t * 72 + k] = hi;
    bb[9984 + t * 72 + k] = lo;
  }
}

// ---------------- S4D conv v5: scan prefixes held in registers across scan-B barrier.
// scan A: batched ILP loads, recurrence in regs, writes group total only;
// fixup: rotates GE into held prefixes, single pack-write. Saves 64 LDS ops/thread
// + the serialized ds_read chain. Everything else identical to proven v4. ----------
__global__ __launch_bounds__(256, 3) void s4d_conv5_kernel(
    const bf16* __restrict__ u_g, bf16* __restrict__ y_g,
    const unsigned short* __restrict__ Bg, const float2* __restrict__ wTg) {
  static __shared__ char __align__(16) sm[51456];
  constexpr int O_U = 0;
  constexpr int O_SH = 10240;
  constexpr int O_SL = 28672;
  constexpr int O_WT = 47104;
  constexpr int O_GE = 47360;
  constexpr int O_GT = 49408;

  int tid = threadIdx.x;
  int lane = tid & 63, wv = tid >> 6;
  int r15 = lane & 15, quad = lane >> 4;
  int bh = blockIdx.x, hh = bh & 127;
  const char* bg0 = (const char*)(Bg + (size_t)hh * 12288);

  {
    const uint4* ug = (const uint4*)(u_g + (size_t)bh * L);
    #pragma unroll
    for (int r = 0; r < 2; ++r) {
      int idx = tid + r * 256;
      *(uint4*)(sm + O_U + (idx >> 2) * 80 + (idx & 3) * 16) = ug[idx];
    }
  }
  if (tid < 32) *(float2*)(sm + O_WT + tid * 8) = wTg[hh * 32 + tid];

  short8v bvh[4], bvl[4];
  #pragma unroll
  for (int nt = 0; nt < 4; ++nt) {
    bvh[nt] = *(const short8v*)(bg0 + 0    + (nt * 16 + r15) * 80 + quad * 16);
    bvl[nt] = *(const short8v*)(bg0 + 5120 + (nt * 16 + r15) * 80 + quad * 16);
  }
  __syncthreads();

  // ---- phase P
  short8v aU0 = *(const short8v*)(sm + O_U + ((wv * 2 + 0) * 16 + r15) * 80 + quad * 16);
  short8v aU1 = *(const short8v*)(sm + O_U + ((wv * 2 + 1) * 16 + r15) * 80 + quad * 16);
  floatx4 cp[2][4];
  #pragma unroll
  for (int mt = 0; mt < 2; ++mt)
    #pragma unroll
    for (int nt = 0; nt < 4; ++nt) cp[mt][nt] = (floatx4){0.f, 0.f, 0.f, 0.f};
  #pragma unroll
  for (int nt = 0; nt < 4; ++nt) {
    cp[0][nt] = __builtin_amdgcn_mfma_f32_16x16x32_bf16(aU0, bvh[nt], cp[0][nt], 0, 0, 0);
    cp[0][nt] = __builtin_amdgcn_mfma_f32_16x16x32_bf16(aU0, bvl[nt], cp[0][nt], 0, 0, 0);
    cp[1][nt] = __builtin_amdgcn_mfma_f32_16x16x32_bf16(aU1, bvh[nt], cp[1][nt], 0, 0, 0);
    cp[1][nt] = __builtin_amdgcn_mfma_f32_16x16x32_bf16(aU1, bvl[nt], cp[1][nt], 0, 0, 0);
  }
  #pragma unroll
  for (int mt = 0; mt < 2; ++mt)
    #pragma unroll
    for (int nt = 0; nt < 4; ++nt) {
      int n2 = nt * 16 + r15;
      int off = ((n2 & 1) ? O_SL : O_SH) + (n2 >> 1) * 4;
      #pragma unroll
      for (int rg = 0; rg < 4; ++rg) {
        int c = (wv * 2 + mt) * 16 + quad * 4 + rg;
        *(float*)(sm + off + c * 144) = cp[mt][nt][rg];
      }
    }
  __syncthreads();

  // ---- scan A: batched loads, recurrence in regs, exclusive prefixes HELD in regs
  int sg = tid >> 5, sn = tid & 31;
  float2 swt = *(const float2*)(sm + O_WT + sn * 8);
  float epr[16], epi[16];
  {
    float pr_[16], pi_[16];
    #pragma unroll
    for (int k = 0; k < 16; ++k) {
      pr_[k] = *(const float*)(sm + O_SH + (sg * 16 + k) * 144 + sn * 4);
      pi_[k] = *(const float*)(sm + O_SL + (sg * 16 + k) * 144 + sn * 4);
    }
    float rr = 0.f, ri = 0.f;
    #pragma unroll
    for (int k = 0; k < 16; ++k) {
      epr[k] = rr; epi[k] = ri;
      float nr = swt.x * rr - swt.y * ri + pr_[k];
      ri = swt.x * ri + swt.y * rr + pi_[k];
      rr = nr;
    }
    *(float2*)(sm + O_GT + (sg * 32 + sn) * 8) = make_float2(rr, ri);
  }
  __syncthreads();
  // ---- scan B: serial over 8 groups; wT^16 via 4 squarings
  if (tid < 32) {
    float2 wt = *(const float2*)(sm + O_WT + tid * 8);
    float w2r = wt.x * wt.x - wt.y * wt.y,   w2i = 2.f * wt.x * wt.y;
    float w4r = w2r * w2r - w2i * w2i,       w4i = 2.f * w2r * w2i;
    float w8r = w4r * w4r - w4i * w4i,       w8i = 2.f * w4r * w4i;
    float w16r = w8r * w8r - w8i * w8i,      w16i = 2.f * w8r * w8i;
    float rr = 0.f, ri = 0.f;
    for (int g = 0; g < 8; ++g) {
      *(float2*)(sm + O_GE + (g * 32 + tid) * 8) = make_float2(rr, ri);
      float2 gt = *(const float2*)(sm + O_GT + (g * 32 + tid) * 8);
      float nr = w16r * rr - w16i * ri + gt.x;
      ri = w16r * ri + w16i * rr + gt.y;
      rr = nr;
    }
  }
  __syncthreads();
  // ---- fixup: E[c] = prefix + wT^k * GE[g]; pack hi/lo and write once
  {
    float2 ge = *(const float2*)(sm + O_GE + (sg * 32 + sn) * 8);
    float ar = ge.x, ai = ge.y;   // wT^0 * GE
    #pragma unroll
    for (int k = 0; k < 16; ++k) {
      int c = sg * 16 + k;
      float er = epr[k] + ar;
      float ei = epi[k] + ai;
      unsigned short hr = f2bs(er), him = f2bs(ei);
      *(unsigned*)(sm + O_SH + c * 144 + sn * 4) = ((unsigned)him << 16) | hr;
      *(unsigned*)(sm + O_SL + c * 144 + sn * 4) =
          ((unsigned)f2bs(ei - bu2f(him)) << 16) | f2bs(er - bu2f(hr));
      float nr = ar * swt.x - ai * swt.y;   // advance wT^k * GE
      ai = ar * swt.y + ai * swt.x;
      ar = nr;
    }
  }
  __syncthreads();

  // ---- Toeplitz + modal MFMAs (K/W frags direct from L2)
  floatx4 acc[2][2];
  #pragma unroll
  for (int mt = 0; mt < 2; ++mt)
    #pragma unroll
    for (int nt = 0; nt < 2; ++nt) acc[mt][nt] = (floatx4){0.f, 0.f, 0.f, 0.f};
  #pragma unroll
  for (int nt = 0; nt < 2; ++nt) {
    short8v kh = *(const short8v*)(bg0 + 10240 + (nt * 16 + r15) * 80 + quad * 16);
    short8v kl = *(const short8v*)(bg0 + 12800 + (nt * 16 + r15) * 80 + quad * 16);
    acc[0][nt] = __builtin_amdgcn_mfma_f32_16x16x32_bf16(aU0, kh, acc[0][nt], 0, 0, 0);
    acc[0][nt] = __builtin_amdgcn_mfma_f32_16x16x32_bf16(aU0, kl, acc[0][nt], 0, 0, 0);
    acc[1][nt] = __builtin_amdgcn_mfma_f32_16x16x32_bf16(aU1, kh, acc[1][nt], 0, 0, 0);
    acc[1][nt] = __builtin_amdgcn_mfma_f32_16x16x32_bf16(aU1, kl, acc[1][nt], 0, 0, 0);
  }
  #pragma unroll
  for (int ks = 0; ks < 2; ++ks) {
    short8v sh0 = *(const short8v*)(sm + O_SH + ((wv * 2 + 0) * 16 + r15) * 144 + ks * 64 + quad * 16);
    short8v sh1 = *(const short8v*)(sm + O_SH + ((wv * 2 + 1) * 16 + r15) * 144 + ks * 64 + quad * 16);
    short8v sl0 = *(const short8v*)(sm + O_SL + ((wv * 2 + 0) * 16 + r15) * 144 + ks * 64 + quad * 16);
    short8v sl1 = *(const short8v*)(sm + O_SL + ((wv * 2 + 1) * 16 + r15) * 144 + ks * 64 + quad * 16);
    #pragma unroll
    for (int nt = 0; nt < 2; ++nt) {
      short8v wh = *(const short8v*)(bg0 + 15360 + (nt * 16 + r15) * 144 + ks * 64 + quad * 16);
      short8v wl = *(const short8v*)(bg0 + 19968 + (nt * 16 + r15) * 144 + ks * 64 + quad * 16);
      acc[0][nt] = __builtin_amdgcn_mfma_f32_16x16x32_bf16(sh0, wh, acc[0][nt], 0, 0, 0);
      acc[0][nt] = __builtin_amdgcn_mfma_f32_16x16x32_bf16(sh0, wl, acc[0][nt], 0, 0, 0);
      acc[0][nt] = __builtin_amdgcn_mfma_f32_16x16x32_bf16(sl0, wh, acc[0][nt], 0, 0, 0);
      acc[1][nt] = __builtin_amdgcn_mfma_f32_16x16x32_bf16(sh1, wh, acc[1][nt], 0, 0, 0);
      acc[1][nt] = __builtin_amdgcn_mfma_f32_16x16x32_bf16(sh1, wl, acc[1][nt], 0, 0, 0);
      acc[1][nt] = __builtin_amdgcn_mfma_f32_16x16x32_bf16(sl1, wh, acc[1][nt], 0, 0, 0);
    }
  }

  #pragma unroll
  for (int mt = 0; mt < 2; ++mt)
    #pragma unroll
    for (int nt = 0; nt < 2; ++nt)
      #pragma unroll
      for (int rg = 0; rg < 4; ++rg) {
        int c = (wv * 2 + mt) * 16 + quad * 4 + rg;
        int t = nt * 16 + r15;
        float v = acc[mt][nt][rg];
        v = 0.5f * v * (1.f + erff(v * 0.70710678118654752f));
        *(unsigned short*)(sm + O_U + (c * 32 + t) * 2) = f2bs(v);
      }
  __syncthreads();
  {
    uint4* yo = (uint4*)(y_g + (size_t)bh * L);
    #pragma unroll
    for (int r = 0; r < 2; ++r) {
      int idx = tid + r * 256;
      yo[idx] = *(const uint4*)(sm + O_U + idx * 16);
    }
  }
}

// ------- pointwise conv + GLU + residual + LN v10 (R15, proven spill-free) -------
__global__ __launch_bounds__(256, 2) void glu_ln10_kernel(
    const unsigned short* __restrict__ y_g, unsigned short* __restrict__ h_g,
    const unsigned short* __restrict__ Wb,  // layer: [hi 256x128] shorts
    const float* __restrict__ ob, const float* __restrict__ lg,
    const float* __restrict__ lb) {
  static __shared__ char __align__(16) sm[36864];
  constexpr int O_Y = 0;        // y transposed [64 pos][136 ch-shorts] = 17408 B (row 272 B)
  constexpr int O_H = 17408;    // h natural [128 ch][68 pos-shorts] = 17408 B; z aliases in-place
  constexpr int O_P = 34816;    // LN partials [4 waves][64 pos] float2 = 2048 B

  int tid = threadIdx.x;
  int wv = tid >> 6, lane = tid & 63, r15 = lane & 15, quad = lane >> 4;
  int b = blockIdx.x >> 4, seg = blockIdx.x & 15;

  float ba[2][4], bgl[2][4];
  #pragma unroll
  for (int i = 0; i < 2; ++i) {
    int ch0 = (2 * wv + i) * 16 + quad * 4;
    #pragma unroll
    for (int rg = 0; rg < 4; ++rg) {
      ba[i][rg]  = ob[ch0 + rg];
      bgl[i][rg] = ob[128 + ch0 + rg];
    }
  }

  for (int t = 0; t < 4; ++t) {
    int l0 = seg * 256 + t * 64;
    {
      int k = tid >> 1, half = tid & 1;
      const uint4* src = (const uint4*)(y_g + ((size_t)(b * H + k)) * L + l0 + half * 32);
      unsigned short sarr[32];
      uint4* sp = (uint4*)sarr;
      sp[0] = src[0]; sp[1] = src[1]; sp[2] = src[2]; sp[3] = src[3];
      #pragma unroll
      for (int j = 0; j < 32; ++j)
        *(unsigned short*)(sm + O_Y + (half * 32 + j) * 272 + k * 2) = sarr[j];
    }
    {
      #pragma unroll
      for (int i = 0; i < 4; ++i) {
        int id = tid + i * 256;           // 0..1023
        int ch = id >> 3, part = id & 7;
        uint4 v = *(const uint4*)(h_g + ((size_t)(b * H + ch)) * L + l0 + part * 8);
        *(uint4*)(sm + O_H + ch * 136 + part * 16) = v;
      }
    }
    __syncthreads();   // A

    float s1[4] = {0.f, 0.f, 0.f, 0.f}, s2[4] = {0.f, 0.f, 0.f, 0.f};
    #pragma unroll
    for (int pt = 0; pt < 4; ++pt) {
      short8v bf[4];
      #pragma unroll
      for (int ks = 0; ks < 4; ++ks)
        bf[ks] = *(const short8v*)(sm + O_Y + (pt * 16 + r15) * 272 + ks * 64 + quad * 16);
      int pos = pt * 16 + r15;
      #pragma unroll
      for (int i = 0; i < 2; ++i) {
        int ch0 = (2 * wv + i) * 16 + quad * 4;
        const unsigned short* wa = Wb + (size_t)((2 * wv + i) * 16 + r15) * 128 + quad * 8;
        floatx4 acca = (floatx4){0.f, 0.f, 0.f, 0.f};
        #pragma unroll
        for (int ks = 0; ks < 4; ++ks) {
          short8v wf = *(const short8v*)(wa + ks * 32);
          acca = __builtin_amdgcn_mfma_f32_16x16x32_bf16(wf, bf[ks], acca, 0, 0, 0);
        }
        const unsigned short* wg = Wb + (size_t)((8 + 2 * wv + i) * 16 + r15) * 128 + quad * 8;
        floatx4 accg = (floatx4){0.f, 0.f, 0.f, 0.f};
        #pragma unroll
        for (int ks = 0; ks < 4; ++ks) {
          short8v wf = *(const short8v*)(wg + ks * 32);
          accg = __builtin_amdgcn_mfma_f32_16x16x32_bf16(wf, bf[ks], accg, 0, 0, 0);
        }
        #pragma unroll
        for (int rg = 0; rg < 4; ++rg) {
          float a = acca[rg] + ba[i][rg];
          float g = accg[rg] + bgl[i][rg];
          float zz = a / (1.f + expf(-g));
          char* slot = sm + O_H + (ch0 + rg) * 136 + pos * 2;
          zz += bu2f(*(const unsigned short*)slot);   // residual read
          s1[pt] += zz;
          s2[pt] += zz * zz;
          *(unsigned short*)slot = f2bs(zz);          // z write, same slot, same lane
        }
      }
    }
    #pragma unroll
    for (int pt = 0; pt < 4; ++pt) {
      s1[pt] += __shfl_xor(s1[pt], 16, 64); s1[pt] += __shfl_xor(s1[pt], 32, 64);
      s2[pt] += __shfl_xor(s2[pt], 16, 64); s2[pt] += __shfl_xor(s2[pt], 32, 64);
    }
    if (quad == 0) {
      #pragma unroll
      for (int pt = 0; pt < 4; ++pt)
        *(float2*)(sm + O_P + (wv * 64 + pt * 16 + r15) * 8) = make_float2(s1[pt], s2[pt]);
    }
    __syncthreads();   // B

    if (tid < 64) {
      float a1 = 0.f, a2 = 0.f;
      #pragma unroll
      for (int w = 0; w < 4; ++w) {
        float2 p = *(const float2*)(sm + O_P + (w * 64 + tid) * 8);
        a1 += p.x; a2 += p.y;
      }
      float m = a1 * (1.f / H);
      float var = a2 * (1.f / H) - m * m;
      if (var < 0.f) var = 0.f;
      *(float2*)(sm + O_P + tid * 8) = make_float2(m, rsqrtf(var + 1e-5f));
    }
    __syncthreads();   // C

    {
      int ch = tid >> 1, half = tid & 1;
      float gg = lg[ch], bb2 = lb[ch];
      unsigned outw[16];
      #pragma unroll
      for (int j = 0; j < 32; ++j) {
        float zz = bu2f(*(const unsigned short*)(sm + O_H + ch * 136 + (half * 32 + j) * 2));
        float2 mr = *(const float2*)(sm + O_P + (half * 32 + j) * 8);
        float v = (zz - mr.x) * mr.y * gg + bb2;
        unsigned short bits = f2bs(v);
        if (j & 1) outw[j >> 1] |= (unsigned)bits << 16;
        else       outw[j >> 1]  = (unsigned)bits;
      }
      uint4* dst = (uint4*)(h_g + ((size_t)(b * H + ch)) * L + l0 + half * 32);
      #pragma unroll
      for (int j = 0; j < 4; ++j)
        dst[j] = *(const uint4*)(&outw[j * 4]);
    }
    __syncthreads();   // D
  }
}

__global__ __launch_bounds__(256) void pool_kernel(const bf16* __restrict__ h_g,
                                                   float* __restrict__ pooled) {
  int bh = blockIdx.x;
  const bf16* row = h_g + (size_t)bh * L;
  float s = 0.f;
  for (int l = threadIdx.x; l < L; l += 256) s += b2f(row[l]);
  for (int off = 32; off > 0; off >>= 1) s += __shfl_down(s, off);
  __shared__ float wsum[4];
  int lane = threadIdx.x & 63, wv = threadIdx.x >> 6;
  if (lane == 0) wsum[wv] = s;
  __syncthreads();
  if (threadIdx.x == 0)
    pooled[bh] = (wsum[0] + wsum[1] + wsum[2] + wsum[3]) * (1.f / L);
}

__global__ void head_kernel(const float* __restrict__ pooled,
                            const float* __restrict__ head_W,
                            const float* __restrict__ head_b,
                            float* __restrict__ out) {
  int tid = threadIdx.x;
  if (tid >= B * 2) return;
  int b = tid >> 1, o = tid & 1;
  float acc = head_b[o];
  for (int ch = 0; ch < H; ++ch)
    acc += pooled[b * H + ch] * head_W[ch * 2 + o];
  out[tid] = acc;
}

extern "C" void kernel_launch(void* const* d_in, const int* in_sizes, int n_in,
                              void* d_out, int out_size, void* d_ws, size_t ws_size,
                              hipStream_t stream) {
  const float* x          = (const float*)d_in[0];
  const float* enc_W      = (const float*)d_in[1];
  const float* enc_b      = (const float*)d_in[2];
  const float* log_dt     = (const float*)d_in[3];
  const float* C_re       = (const float*)d_in[4];
  const float* C_im       = (const float*)d_in[5];
  const float* log_A_real = (const float*)d_in[6];
  const float* A_imag     = (const float*)d_in[7];
  const float* Dp         = (const float*)d_in[8];
  const float* out_W      = (const float*)d_in[9];
  const float* out_b      = (const float*)d_in[10];
  const float* ln_g       = (const float*)d_in[11];
  const float* ln_b       = (const float*)d_in[12];
  const float* head_W     = (const float*)d_in[13];
  const float* head_b     = (const float*)d_in[14];

  // ws: hbuf bf16 32MB | ybuf bf16 32MB | Wb bf16 hi/lo 1.5MB | pooled | Bg 3MB | wTg
  bf16* hbuf = (bf16*)d_ws;
  bf16* ybuf = hbuf + (size_t)B * H * L;
  unsigned short* Wb = (unsigned short*)(ybuf + (size_t)B * H * L);
  float* pooled = (float*)(Wb + (size_t)NL * 65536);
  unsigned short* Bg = (unsigned short*)(pooled + B * H);
  float2* wTg = (float2*)(Bg + (size_t)12288 * H);

  encoder_kernel<<<B * H, 256, 0, stream>>>(x, enc_W, enc_b, hbuf);
  w_prep_kernel<<<(NL * 2 * H * H + 255) / 256, 256, 0, stream>>>(out_W, Wb);

  for (int layer = 0; layer < NL; ++layer) {
    s4d_prep_kernel<<<H, 256, 0, stream>>>(log_dt, C_re, C_im, log_A_real,
                                           A_imag, Dp, Bg, wTg, layer);
    s4d_conv5_kernel<<<B * H, 256, 0, stream>>>(hbuf, ybuf, Bg, wTg);
    glu_ln10_kernel<<<B * 16, 256, 0, stream>>>(
        (const unsigned short*)ybuf, (unsigned short*)hbuf,
        Wb + (size_t)layer * 65536, out_b + layer * 2 * H,
        ln_g + layer * H, ln_b + layer * H);
  }

  pool_kernel<<<B * H, 256, 0, stream>>>(hbuf, pooled);
  head_kernel<<<1, 64, 0, stream>>>(pooled, head_W, head_b, (float*)d_out);
}

// Round 17
// 622.565 us; speedup vs baseline: 1.5996x; 1.1296x over previous
//
#include <hip/hip_runtime.h>
#include <hip/hip_bf16.h>

#define B 32
#define H 128
#define L 4096
#define NC 32
#define NL 6
#define NCHUNK 128

typedef __hip_bfloat16 bf16;
typedef __attribute__((ext_vector_type(8))) short short8v;   // 8 bf16 (4 VGPR)
typedef __attribute__((ext_vector_type(4))) float floatx4;   // MFMA C/D

__device__ __forceinline__ float b2f(bf16 v) { return __bfloat162float(v); }
__device__ __forceinline__ float bu2f(unsigned int u) {
  union { unsigned int i; float f; } v; v.i = u << 16; return v.f;
}
// float -> bf16 bits, round-to-nearest-even
__device__ __forceinline__ unsigned short f2bs(float f) {
  unsigned u = __float_as_uint(f);
  u = (u + 0x7fffu + ((u >> 16) & 1u)) >> 16;
  return (unsigned short)u;
}

// ---------------- encoder ----------------
__global__ void encoder_kernel(const float* __restrict__ x, const float* __restrict__ enc_W,
                               const float* __restrict__ enc_b, bf16* __restrict__ h) {
  int blk = blockIdx.x;
  int b = blk >> 7, ch = blk & 127;
  float w0 = enc_W[ch];
  float w1 = enc_W[H + ch];
  float bb = enc_b[ch];
  const float* x0 = x + (size_t)b * 2 * L;
  const float* x1 = x0 + L;
  bf16* out = h + ((size_t)b * H + ch) * L;
  for (int l = threadIdx.x; l < L; l += blockDim.x)
    out[l] = __float2bfloat16(x0[l] * w0 + x1[l] * w1 + bb);
}

// Wb[l][hl][o][k]: hi/lo bf16 split of out_W[l][o][k]; per-layer stride 65536
// (glu uses only the hi plane)
__global__ void w_prep_kernel(const float* __restrict__ out_W, unsigned short* __restrict__ Wb) {
  int idx = blockIdx.x * 256 + threadIdx.x;
  if (idx >= NL * 2 * H * H) return;
  int l = idx / (2 * H * H);
  int rem = idx % (2 * H * H);
  float v = out_W[idx];
  unsigned short hi = f2bs(v);
  unsigned short lo = f2bs(v - bu2f(hi));
  Wb[(size_t)l * 65536 + rem] = hi;
  Wb[(size_t)l * 65536 + 32768 + rem] = lo;
}

// ---------------- per-(layer,h) B-matrix precompute: ALL LAYERS IN ONE DISPATCH ----------------
// grid = NL*H = 768 blocks; block handles (layer = blk>>7, h = blk&127).
__global__ __launch_bounds__(256) void s4d_prep_all_kernel(
    const float* __restrict__ log_dt, const float* __restrict__ C_re,
    const float* __restrict__ C_im, const float* __restrict__ log_A_real,
    const float* __restrict__ A_imag, const float* __restrict__ Dp,
    unsigned short* __restrict__ Bg, float2* __restrict__ wTg) {
  __shared__ float2 dta_s[NC], cd_s[NC];
  __shared__ float K_s[32];
  int lh = blockIdx.x;
  int layer = lh >> 7, h = lh & 127;
  int tid = threadIdx.x;
  if (tid < NC) {
    int n = tid, base = (layer * H + h) * NC + n;
    float dt = expf(log_dt[layer * H + h]);
    float Are = -expf(log_A_real[base]);
    float Aim = A_imag[base];
    float dre = dt * Are, dim = dt * Aim;
    float er = expf(dre);
    float wre = er * cosf(dim), wim = er * sinf(dim);
    float emre = wre - 1.f, emim = wim;   // expm1(dtA)
    float cre = C_re[base], cim = C_im[base];
    float nre = cre * emre - cim * emim, nim = cre * emim + cim * emre;
    float den = Are * Are + Aim * Aim;
    dta_s[n] = make_float2(dre, dim);
    cd_s[n] = make_float2((nre * Are + nim * Aim) / den, (nim * Are - nre * Aim) / den);
    float e32 = expf(dre * 32.f);
    wTg[lh * NC + n] = make_float2(e32 * cosf(dim * 32.f), e32 * sinf(dim * 32.f));
  }
  __syncthreads();
  if (tid < 32) {  // K[tau] = 2 sum_n Re(cd_n w_n^tau)
    float acc = 0.f;
    float tau = (float)tid;
    for (int n = 0; n < NC; ++n) {
      float e = expf(dta_s[n].x * tau);
      float pr = e * cosf(dta_s[n].y * tau), pi = e * sinf(dta_s[n].y * tau);
      acc += cd_s[n].x * pr - cd_s[n].y * pi;
    }
    K_s[tid] = 2.f * acc;
  }
  __syncthreads();
  unsigned short* bb = Bg + (size_t)lh * 12288;
  float Dv = Dp[layer * H + h];
  #pragma unroll
  for (int i = 0; i < 8; ++i) {     // VT: 2048 entries
    int idx = tid + i * 256;
    int n2 = idx >> 5, t = idx & 31, n = n2 >> 1;
    float k = (float)(31 - t);
    float e = expf(dta_s[n].x * k);
    float v = (n2 & 1) ? e * sinf(dta_s[n].y * k) : e * cosf(dta_s[n].y * k);
    unsigned short hi = f2bs(v);
    unsigned short lo = f2bs(v - bu2f(hi));
    bb[n2 * 40 + t] = hi;
    bb[2560 + n2 * 40 + t] = lo;
  }
  #pragma unroll
  for (int i = 0; i < 4; ++i) {     // KT: 1024 entries
    int idx = tid + i * 256;
    int t = idx >> 5, m = idx & 31;
    float v = (m > t) ? 0.f : (K_s[t - m] + (m == t ? Dv : 0.f));
    unsigned short hi = f2bs(v);
    unsigned short lo = f2bs(v - bu2f(hi));
    bb[5120 + t * 40 + m] = hi;
    bb[6400 + t * 40 + m] = lo;
  }
  #pragma unroll
  for (int i = 0; i < 8; ++i) {     // WT: 2048 entries
    int idx = tid + i * 256;
    int t = idx >> 6, k = idx & 63, n = k >> 1;
    float tp = (float)(t + 1);
    float e = expf(dta_s[n].x * tp);
    float pr = e * cosf(dta_s[n].y * tp), pi = e * sinf(dta_s[n].y * tp);
    float cwr = cd_s[n].x * pr - cd_s[n].y * pi;
    float cwi = cd_s[n].x * pi + cd_s[n].y * pr;
    float v = (k & 1) ? -2.f * cwi : 2.f * cwr;
    unsigned short hi = f2bs(v);
    unsigned short lo = f2bs(v - bu2f(hi));
    bb[7680 + t * 72 + k] = hi;
    bb[9984 + t * 72 + k] = lo;
  }
}

// ---------------- S4D conv v5 (R16, proven): scan prefixes in regs across scan-B ----------------
__global__ __launch_bounds__(256, 3) void s4d_conv5_kernel(
    const bf16* __restrict__ u_g, bf16* __restrict__ y_g,
    const unsigned short* __restrict__ Bg, const float2* __restrict__ wTg) {
  static __shared__ char __align__(16) sm[51456];
  constexpr int O_U = 0;
  constexpr int O_SH = 10240;
  constexpr int O_SL = 28672;
  constexpr int O_WT = 47104;
  constexpr int O_GE = 47360;
  constexpr int O_GT = 49408;

  int tid = threadIdx.x;
  int lane = tid & 63, wv = tid >> 6;
  int r15 = lane & 15, quad = lane >> 4;
  int bh = blockIdx.x, hh = bh & 127;
  const char* bg0 = (const char*)(Bg + (size_t)hh * 12288);

  {
    const uint4* ug = (const uint4*)(u_g + (size_t)bh * L);
    #pragma unroll
    for (int r = 0; r < 2; ++r) {
      int idx = tid + r * 256;
      *(uint4*)(sm + O_U + (idx >> 2) * 80 + (idx & 3) * 16) = ug[idx];
    }
  }
  if (tid < 32) *(float2*)(sm + O_WT + tid * 8) = wTg[hh * 32 + tid];

  short8v bvh[4], bvl[4];
  #pragma unroll
  for (int nt = 0; nt < 4; ++nt) {
    bvh[nt] = *(const short8v*)(bg0 + 0    + (nt * 16 + r15) * 80 + quad * 16);
    bvl[nt] = *(const short8v*)(bg0 + 5120 + (nt * 16 + r15) * 80 + quad * 16);
  }
  __syncthreads();

  // ---- phase P
  short8v aU0 = *(const short8v*)(sm + O_U + ((wv * 2 + 0) * 16 + r15) * 80 + quad * 16);
  short8v aU1 = *(const short8v*)(sm + O_U + ((wv * 2 + 1) * 16 + r15) * 80 + quad * 16);
  floatx4 cp[2][4];
  #pragma unroll
  for (int mt = 0; mt < 2; ++mt)
    #pragma unroll
    for (int nt = 0; nt < 4; ++nt) cp[mt][nt] = (floatx4){0.f, 0.f, 0.f, 0.f};
  #pragma unroll
  for (int nt = 0; nt < 4; ++nt) {
    cp[0][nt] = __builtin_amdgcn_mfma_f32_16x16x32_bf16(aU0, bvh[nt], cp[0][nt], 0, 0, 0);
    cp[0][nt] = __builtin_amdgcn_mfma_f32_16x16x32_bf16(aU0, bvl[nt], cp[0][nt], 0, 0, 0);
    cp[1][nt] = __builtin_amdgcn_mfma_f32_16x16x32_bf16(aU1, bvh[nt], cp[1][nt], 0, 0, 0);
    cp[1][nt] = __builtin_amdgcn_mfma_f32_16x16x32_bf16(aU1, bvl[nt], cp[1][nt], 0, 0, 0);
  }
  #pragma unroll
  for (int mt = 0; mt < 2; ++mt)
    #pragma unroll
    for (int nt = 0; nt < 4; ++nt) {
      int n2 = nt * 16 + r15;
      int off = ((n2 & 1) ? O_SL : O_SH) + (n2 >> 1) * 4;
      #pragma unroll
      for (int rg = 0; rg < 4; ++rg) {
        int c = (wv * 2 + mt) * 16 + quad * 4 + rg;
        *(float*)(sm + off + c * 144) = cp[mt][nt][rg];
      }
    }
  __syncthreads();

  // ---- scan A: batched loads, recurrence in regs, exclusive prefixes HELD in regs
  int sg = tid >> 5, sn = tid & 31;
  float2 swt = *(const float2*)(sm + O_WT + sn * 8);
  float epr[16], epi[16];
  {
    float pr_[16], pi_[16];
    #pragma unroll
    for (int k = 0; k < 16; ++k) {
      pr_[k] = *(const float*)(sm + O_SH + (sg * 16 + k) * 144 + sn * 4);
      pi_[k] = *(const float*)(sm + O_SL + (sg * 16 + k) * 144 + sn * 4);
    }
    float rr = 0.f, ri = 0.f;
    #pragma unroll
    for (int k = 0; k < 16; ++k) {
      epr[k] = rr; epi[k] = ri;
      float nr = swt.x * rr - swt.y * ri + pr_[k];
      ri = swt.x * ri + swt.y * rr + pi_[k];
      rr = nr;
    }
    *(float2*)(sm + O_GT + (sg * 32 + sn) * 8) = make_float2(rr, ri);
  }
  __syncthreads();
  // ---- scan B: serial over 8 groups; wT^16 via 4 squarings
  if (tid < 32) {
    float2 wt = *(const float2*)(sm + O_WT + tid * 8);
    float w2r = wt.x * wt.x - wt.y * wt.y,   w2i = 2.f * wt.x * wt.y;
    float w4r = w2r * w2r - w2i * w2i,       w4i = 2.f * w2r * w2i;
    float w8r = w4r * w4r - w4i * w4i,       w8i = 2.f * w4r * w4i;
    float w16r = w8r * w8r - w8i * w8i,      w16i = 2.f * w8r * w8i;
    float rr = 0.f, ri = 0.f;
    for (int g = 0; g < 8; ++g) {
      *(float2*)(sm + O_GE + (g * 32 + tid) * 8) = make_float2(rr, ri);
      float2 gt = *(const float2*)(sm + O_GT + (g * 32 + tid) * 8);
      float nr = w16r * rr - w16i * ri + gt.x;
      ri = w16r * ri + w16i * rr + gt.y;
      rr = nr;
    }
  }
  __syncthreads();
  // ---- fixup: E[c] = prefix + wT^k * GE[g]; pack hi/lo and write once
  {
    float2 ge = *(const float2*)(sm + O_GE + (sg * 32 + sn) * 8);
    float ar = ge.x, ai = ge.y;   // wT^0 * GE
    #pragma unroll
    for (int k = 0; k < 16; ++k) {
      int c = sg * 16 + k;
      float er = epr[k] + ar;
      float ei = epi[k] + ai;
      unsigned short hr = f2bs(er), him = f2bs(ei);
      *(unsigned*)(sm + O_SH + c * 144 + sn * 4) = ((unsigned)him << 16) | hr;
      *(unsigned*)(sm + O_SL + c * 144 + sn * 4) =
          ((unsigned)f2bs(ei - bu2f(him)) << 16) | f2bs(er - bu2f(hr));
      float nr = ar * swt.x - ai * swt.y;   // advance wT^k * GE
      ai = ar * swt.y + ai * swt.x;
      ar = nr;
    }
  }
  __syncthreads();

  // ---- Toeplitz + modal MFMAs (K/W frags direct from L2)
  floatx4 acc[2][2];
  #pragma unroll
  for (int mt = 0; mt < 2; ++mt)
    #pragma unroll
    for (int nt = 0; nt < 2; ++nt) acc[mt][nt] = (floatx4){0.f, 0.f, 0.f, 0.f};
  #pragma unroll
  for (int nt = 0; nt < 2; ++nt) {
    short8v kh = *(const short8v*)(bg0 + 10240 + (nt * 16 + r15) * 80 + quad * 16);
    short8v kl = *(const short8v*)(bg0 + 12800 + (nt * 16 + r15) * 80 + quad * 16);
    acc[0][nt] = __builtin_amdgcn_mfma_f32_16x16x32_bf16(aU0, kh, acc[0][nt], 0, 0, 0);
    acc[0][nt] = __builtin_amdgcn_mfma_f32_16x16x32_bf16(aU0, kl, acc[0][nt], 0, 0, 0);
    acc[1][nt] = __builtin_amdgcn_mfma_f32_16x16x32_bf16(aU1, kh, acc[1][nt], 0, 0, 0);
    acc[1][nt] = __builtin_amdgcn_mfma_f32_16x16x32_bf16(aU1, kl, acc[1][nt], 0, 0, 0);
  }
  #pragma unroll
  for (int ks = 0; ks < 2; ++ks) {
    short8v sh0 = *(const short8v*)(sm + O_SH + ((wv * 2 + 0) * 16 + r15) * 144 + ks * 64 + quad * 16);
    short8v sh1 = *(const short8v*)(sm + O_SH + ((wv * 2 + 1) * 16 + r15) * 144 + ks * 64 + quad * 16);
    short8v sl0 = *(const short8v*)(sm + O_SL + ((wv * 2 + 0) * 16 + r15) * 144 + ks * 64 + quad * 16);
    short8v sl1 = *(const short8v*)(sm + O_SL + ((wv * 2 + 1) * 16 + r15) * 144 + ks * 64 + quad * 16);
    #pragma unroll
    for (int nt = 0; nt < 2; ++nt) {
      short8v wh = *(const short8v*)(bg0 + 15360 + (nt * 16 + r15) * 144 + ks * 64 + quad * 16);
      short8v wl = *(const short8v*)(bg0 + 19968 + (nt * 16 + r15) * 144 + ks * 64 + quad * 16);
      acc[0][nt] = __builtin_amdgcn_mfma_f32_16x16x32_bf16(sh0, wh, acc[0][nt], 0, 0, 0);
      acc[0][nt] = __builtin_amdgcn_mfma_f32_16x16x32_bf16(sh0, wl, acc[0][nt], 0, 0, 0);
      acc[0][nt] = __builtin_amdgcn_mfma_f32_16x16x32_bf16(sl0, wh, acc[0][nt], 0, 0, 0);
      acc[1][nt] = __builtin_amdgcn_mfma_f32_16x16x32_bf16(sh1, wh, acc[1][nt], 0, 0, 0);
      acc[1][nt] = __builtin_amdgcn_mfma_f32_16x16x32_bf16(sh1, wl, acc[1][nt], 0, 0, 0);
      acc[1][nt] = __builtin_amdgcn_mfma_f32_16x16x32_bf16(sl1, wh, acc[1][nt], 0, 0, 0);
    }
  }

  #pragma unroll
  for (int mt = 0; mt < 2; ++mt)
    #pragma unroll
    for (int nt = 0; nt < 2; ++nt)
      #pragma unroll
      for (int rg = 0; rg < 4; ++rg) {
        int c = (wv * 2 + mt) * 16 + quad * 4 + rg;
        int t = nt * 16 + r15;
        float v = acc[mt][nt][rg];
        v = 0.5f * v * (1.f + erff(v * 0.70710678118654752f));
        *(unsigned short*)(sm + O_U + (c * 32 + t) * 2) = f2bs(v);
      }
  __syncthreads();
  {
    uint4* yo = (uint4*)(y_g + (size_t)bh * L);
    #pragma unroll
    for (int r = 0; r < 2; ++r) {
      int idx = tid + r * 256;
      yo[idx] = *(const uint4*)(sm + O_U + idx * 16);
    }
  }
}

// ------- pointwise conv + GLU + residual + LN v10 (R15/R16, proven spill-free) -------
__global__ __launch_bounds__(256, 2) void glu_ln10_kernel(
    const unsigned short* __restrict__ y_g, unsigned short* __restrict__ h_g,
    const unsigned short* __restrict__ Wb,  // layer: [hi 256x128] shorts
    const float* __restrict__ ob, const float* __restrict__ lg,
    const float* __restrict__ lb) {
  static __shared__ char __align__(16) sm[36864];
  constexpr int O_Y = 0;        // y transposed [64 pos][136 ch-shorts] = 17408 B (row 272 B)
  constexpr int O_H = 17408;    // h natural [128 ch][68 pos-shorts] = 17408 B; z aliases in-place
  constexpr int O_P = 34816;    // LN partials [4 waves][64 pos] float2 = 2048 B

  int tid = threadIdx.x;
  int wv = tid >> 6, lane = tid & 63, r15 = lane & 15, quad = lane >> 4;
  int b = blockIdx.x >> 4, seg = blockIdx.x & 15;

  float ba[2][4], bgl[2][4];
  #pragma unroll
  for (int i = 0; i < 2; ++i) {
    int ch0 = (2 * wv + i) * 16 + quad * 4;
    #pragma unroll
    for (int rg = 0; rg < 4; ++rg) {
      ba[i][rg]  = ob[ch0 + rg];
      bgl[i][rg] = ob[128 + ch0 + rg];
    }
  }

  for (int t = 0; t < 4; ++t) {
    int l0 = seg * 256 + t * 64;
    {
      int k = tid >> 1, half = tid & 1;
      const uint4* src = (const uint4*)(y_g + ((size_t)(b * H + k)) * L + l0 + half * 32);
      unsigned short sarr[32];
      uint4* sp = (uint4*)sarr;
      sp[0] = src[0]; sp[1] = src[1]; sp[2] = src[2]; sp[3] = src[3];
      #pragma unroll
      for (int j = 0; j < 32; ++j)
        *(unsigned short*)(sm + O_Y + (half * 32 + j) * 272 + k * 2) = sarr[j];
    }
    {
      #pragma unroll
      for (int i = 0; i < 4; ++i) {
        int id = tid + i * 256;           // 0..1023
        int ch = id >> 3, part = id & 7;
        uint4 v = *(const uint4*)(h_g + ((size_t)(b * H + ch)) * L + l0 + part * 8);
        *(uint4*)(sm + O_H + ch * 136 + part * 16) = v;
      }
    }
    __syncthreads();   // A

    float s1[4] = {0.f, 0.f, 0.f, 0.f}, s2[4] = {0.f, 0.f, 0.f, 0.f};
    #pragma unroll
    for (int pt = 0; pt < 4; ++pt) {
      short8v bf[4];
      #pragma unroll
      for (int ks = 0; ks < 4; ++ks)
        bf[ks] = *(const short8v*)(sm + O_Y + (pt * 16 + r15) * 272 + ks * 64 + quad * 16);
      int pos = pt * 16 + r15;
      #pragma unroll
      for (int i = 0; i < 2; ++i) {
        int ch0 = (2 * wv + i) * 16 + quad * 4;
        const unsigned short* wa = Wb + (size_t)((2 * wv + i) * 16 + r15) * 128 + quad * 8;
        floatx4 acca = (floatx4){0.f, 0.f, 0.f, 0.f};
        #pragma unroll
        for (int ks = 0; ks < 4; ++ks) {
          short8v wf = *(const short8v*)(wa + ks * 32);
          acca = __builtin_amdgcn_mfma_f32_16x16x32_bf16(wf, bf[ks], acca, 0, 0, 0);
        }
        const unsigned short* wg = Wb + (size_t)((8 + 2 * wv + i) * 16 + r15) * 128 + quad * 8;
        floatx4 accg = (floatx4){0.f, 0.f, 0.f, 0.f};
        #pragma unroll
        for (int ks = 0; ks < 4; ++ks) {
          short8v wf = *(const short8v*)(wg + ks * 32);
          accg = __builtin_amdgcn_mfma_f32_16x16x32_bf16(wf, bf[ks], accg, 0, 0, 0);
        }
        #pragma unroll
        for (int rg = 0; rg < 4; ++rg) {
          float a = acca[rg] + ba[i][rg];
          float g = accg[rg] + bgl[i][rg];
          float zz = a / (1.f + expf(-g));
          char* slot = sm + O_H + (ch0 + rg) * 136 + pos * 2;
          zz += bu2f(*(const unsigned short*)slot);   // residual read
          s1[pt] += zz;
          s2[pt] += zz * zz;
          *(unsigned short*)slot = f2bs(zz);          // z write, same slot, same lane
        }
      }
    }
    #pragma unroll
    for (int pt = 0; pt < 4; ++pt) {
      s1[pt] += __shfl_xor(s1[pt], 16, 64); s1[pt] += __shfl_xor(s1[pt], 32, 64);
      s2[pt] += __shfl_xor(s2[pt], 16, 64); s2[pt] += __shfl_xor(s2[pt], 32, 64);
    }
    if (quad == 0) {
      #pragma unroll
      for (int pt = 0; pt < 4; ++pt)
        *(float2*)(sm + O_P + (wv * 64 + pt * 16 + r15) * 8) = make_float2(s1[pt], s2[pt]);
    }
    __syncthreads();   // B

    if (tid < 64) {
      float a1 = 0.f, a2 = 0.f;
      #pragma unroll
      for (int w = 0; w < 4; ++w) {
        float2 p = *(const float2*)(sm + O_P + (w * 64 + tid) * 8);
        a1 += p.x; a2 += p.y;
      }
      float m = a1 * (1.f / H);
      float var = a2 * (1.f / H) - m * m;
      if (var < 0.f) var = 0.f;
      *(float2*)(sm + O_P + tid * 8) = make_float2(m, rsqrtf(var + 1e-5f));
    }
    __syncthreads();   // C

    {
      int ch = tid >> 1, half = tid & 1;
      float gg = lg[ch], bb2 = lb[ch];
      unsigned outw[16];
      #pragma unroll
      for (int j = 0; j < 32; ++j) {
        float zz = bu2f(*(const unsigned short*)(sm + O_H + ch * 136 + (half * 32 + j) * 2));
        float2 mr = *(const float2*)(sm + O_P + (half * 32 + j) * 8);
        float v = (zz - mr.x) * mr.y * gg + bb2;
        unsigned short bits = f2bs(v);
        if (j & 1) outw[j >> 1] |= (unsigned)bits << 16;
        else       outw[j >> 1]  = (unsigned)bits;
      }
      uint4* dst = (uint4*)(h_g + ((size_t)(b * H + ch)) * L + l0 + half * 32);
      #pragma unroll
      for (int j = 0; j < 4; ++j)
        dst[j] = *(const uint4*)(&outw[j * 4]);
    }
    __syncthreads();   // D
  }
}

__global__ __launch_bounds__(256) void pool_kernel(const bf16* __restrict__ h_g,
                                                   float* __restrict__ pooled) {
  int bh = blockIdx.x;
  const bf16* row = h_g + (size_t)bh * L;
  float s = 0.f;
  for (int l = threadIdx.x; l < L; l += 256) s += b2f(row[l]);
  for (int off = 32; off > 0; off >>= 1) s += __shfl_down(s, off);
  __shared__ float wsum[4];
  int lane = threadIdx.x & 63, wv = threadIdx.x >> 6;
  if (lane == 0) wsum[wv] = s;
  __syncthreads();
  if (threadIdx.x == 0)
    pooled[bh] = (wsum[0] + wsum[1] + wsum[2] + wsum[3]) * (1.f / L);
}

__global__ void head_kernel(const float* __restrict__ pooled,
                            const float* __restrict__ head_W,
                            const float* __restrict__ head_b,
                            float* __restrict__ out) {
  int tid = threadIdx.x;
  if (tid >= B * 2) return;
  int b = tid >> 1, o = tid & 1;
  float acc = head_b[o];
  for (int ch = 0; ch < H; ++ch)
    acc += pooled[b * H + ch] * head_W[ch * 2 + o];
  out[tid] = acc;
}

extern "C" void kernel_launch(void* const* d_in, const int* in_sizes, int n_in,
                              void* d_out, int out_size, void* d_ws, size_t ws_size,
                              hipStream_t stream) {
  const float* x          = (const float*)d_in[0];
  const float* enc_W      = (const float*)d_in[1];
  const float* enc_b      = (const float*)d_in[2];
  const float* log_dt     = (const float*)d_in[3];
  const float* C_re       = (const float*)d_in[4];
  const float* C_im       = (const float*)d_in[5];
  const float* log_A_real = (const float*)d_in[6];
  const float* A_imag     = (const float*)d_in[7];
  const float* Dp         = (const float*)d_in[8];
  const float* out_W      = (const float*)d_in[9];
  const float* out_b      = (const float*)d_in[10];
  const float* ln_g       = (const float*)d_in[11];
  const float* ln_b       = (const float*)d_in[12];
  const float* head_W     = (const float*)d_in[13];
  const float* head_b     = (const float*)d_in[14];

  // ws (~84.6 MB): hbuf bf16 32MB | ybuf bf16 32MB | Wb 1.5MB | pooled 16KB |
  //                Bg (all layers) 18.9MB | wTg (all layers) 196KB
  bf16* hbuf = (bf16*)d_ws;
  bf16* ybuf = hbuf + (size_t)B * H * L;
  unsigned short* Wb = (unsigned short*)(ybuf + (size_t)B * H * L);
  float* pooled = (float*)(Wb + (size_t)NL * 65536);
  unsigned short* Bg = (unsigned short*)(pooled + B * H);
  float2* wTg = (float2*)(Bg + (size_t)NL * H * 12288);

  encoder_kernel<<<B * H, 256, 0, stream>>>(x, enc_W, enc_b, hbuf);
  w_prep_kernel<<<(NL * 2 * H * H + 255) / 256, 256, 0, stream>>>(out_W, Wb);
  s4d_prep_all_kernel<<<NL * H, 256, 0, stream>>>(log_dt, C_re, C_im, log_A_real,
                                                  A_imag, Dp, Bg, wTg);

  for (int layer = 0; layer < NL; ++layer) {
    s4d_conv5_kernel<<<B * H, 256, 0, stream>>>(
        hbuf, ybuf, Bg + (size_t)layer * H * 12288, wTg + (size_t)layer * H * NC);
    glu_ln10_kernel<<<B * 16, 256, 0, stream>>>(
        (const unsigned short*)ybuf, (unsigned short*)hbuf,
        Wb + (size_t)layer * 65536, out_b + layer * 2 * H,
        ln_g + layer * H, ln_b + layer * H);
  }

  pool_kernel<<<B * H, 256, 0, stream>>>(hbuf, pooled);
  head_kernel<<<1, 64, 0, stream>>>(pooled, head_W, head_b, (float*)d_out);
}

// Round 18
// 615.140 us; speedup vs baseline: 1.6189x; 1.0121x over previous
//
#include <hip/hip_runtime.h>
#include <hip/hip_bf16.h>

#define B 32
#define H 128
#define L 4096
#define NC 32
#define NL 6
#define NCHUNK 128

typedef __hip_bfloat16 bf16;
typedef __attribute__((ext_vector_type(8))) short short8v;   // 8 bf16 (4 VGPR)
typedef __attribute__((ext_vector_type(4))) float floatx4;   // MFMA C/D

__device__ __forceinline__ float b2f(bf16 v) { return __bfloat162float(v); }
__device__ __forceinline__ float bu2f(unsigned int u) {
  union { unsigned int i; float f; } v; v.i = u << 16; return v.f;
}
// float -> bf16 bits via HW RNE convert (bit-identical to soft RNE)
__device__ __forceinline__ unsigned short f2bs(float f) {
  bf16 b = __float2bfloat16(f);
  union { bf16 h; unsigned short s; } cv; cv.h = b; return cv.s;
}
// two floats -> packed bf16 dword (a low, b high) via v_cvt_pk_bf16_f32
__device__ __forceinline__ unsigned pack2(float a, float b) {
  union { __hip_bfloat162 h; unsigned u; } cv;
  cv.h = __float22bfloat162_rn(make_float2(a, b));
  return cv.u;
}

// ---------------- encoder ----------------
__global__ void encoder_kernel(const float* __restrict__ x, const float* __restrict__ enc_W,
                               const float* __restrict__ enc_b, bf16* __restrict__ h) {
  int blk = blockIdx.x;
  int b = blk >> 7, ch = blk & 127;
  float w0 = enc_W[ch];
  float w1 = enc_W[H + ch];
  float bb = enc_b[ch];
  const float* x0 = x + (size_t)b * 2 * L;
  const float* x1 = x0 + L;
  bf16* out = h + ((size_t)b * H + ch) * L;
  for (int l = threadIdx.x; l < L; l += blockDim.x)
    out[l] = __float2bfloat16(x0[l] * w0 + x1[l] * w1 + bb);
}

// Wb[l][hl][o][k]: hi/lo bf16 split of out_W[l][o][k]; per-layer stride 65536
__global__ void w_prep_kernel(const float* __restrict__ out_W, unsigned short* __restrict__ Wb) {
  int idx = blockIdx.x * 256 + threadIdx.x;
  if (idx >= NL * 2 * H * H) return;
  int l = idx / (2 * H * H);
  int rem = idx % (2 * H * H);
  float v = out_W[idx];
  unsigned short hi = f2bs(v);
  unsigned short lo = f2bs(v - bu2f(hi));
  Wb[(size_t)l * 65536 + rem] = hi;
  Wb[(size_t)l * 65536 + 32768 + rem] = lo;
}

// ---------------- per-(layer,h) B-matrix precompute: ALL LAYERS IN ONE DISPATCH ----------------
__global__ __launch_bounds__(256) void s4d_prep_all_kernel(
    const float* __restrict__ log_dt, const float* __restrict__ C_re,
    const float* __restrict__ C_im, const float* __restrict__ log_A_real,
    const float* __restrict__ A_imag, const float* __restrict__ Dp,
    unsigned short* __restrict__ Bg, float2* __restrict__ wTg) {
  __shared__ float2 dta_s[NC], cd_s[NC];
  __shared__ float K_s[32];
  int lh = blockIdx.x;
  int layer = lh >> 7, h = lh & 127;
  int tid = threadIdx.x;
  if (tid < NC) {
    int n = tid, base = (layer * H + h) * NC + n;
    float dt = expf(log_dt[layer * H + h]);
    float Are = -expf(log_A_real[base]);
    float Aim = A_imag[base];
    float dre = dt * Are, dim = dt * Aim;
    float er = expf(dre);
    float wre = er * cosf(dim), wim = er * sinf(dim);
    float emre = wre - 1.f, emim = wim;   // expm1(dtA)
    float cre = C_re[base], cim = C_im[base];
    float nre = cre * emre - cim * emim, nim = cre * emim + cim * emre;
    float den = Are * Are + Aim * Aim;
    dta_s[n] = make_float2(dre, dim);
    cd_s[n] = make_float2((nre * Are + nim * Aim) / den, (nim * Are - nre * Aim) / den);
    float e32 = expf(dre * 32.f);
    wTg[lh * NC + n] = make_float2(e32 * cosf(dim * 32.f), e32 * sinf(dim * 32.f));
  }
  __syncthreads();
  if (tid < 32) {  // K[tau] = 2 sum_n Re(cd_n w_n^tau)
    float acc = 0.f;
    float tau = (float)tid;
    for (int n = 0; n < NC; ++n) {
      float e = expf(dta_s[n].x * tau);
      float pr = e * cosf(dta_s[n].y * tau), pi = e * sinf(dta_s[n].y * tau);
      acc += cd_s[n].x * pr - cd_s[n].y * pi;
    }
    K_s[tid] = 2.f * acc;
  }
  __syncthreads();
  unsigned short* bb = Bg + (size_t)lh * 12288;
  float Dv = Dp[layer * H + h];
  #pragma unroll
  for (int i = 0; i < 8; ++i) {     // VT: 2048 entries
    int idx = tid + i * 256;
    int n2 = idx >> 5, t = idx & 31, n = n2 >> 1;
    float k = (float)(31 - t);
    float e = expf(dta_s[n].x * k);
    float v = (n2 & 1) ? e * sinf(dta_s[n].y * k) : e * cosf(dta_s[n].y * k);
    unsigned short hi = f2bs(v);
    unsigned short lo = f2bs(v - bu2f(hi));
    bb[n2 * 40 + t] = hi;
    bb[2560 + n2 * 40 + t] = lo;
  }
  #pragma unroll
  for (int i = 0; i < 4; ++i) {     // KT: 1024 entries
    int idx = tid + i * 256;
    int t = idx >> 5, m = idx & 31;
    float v = (m > t) ? 0.f : (K_s[t - m] + (m == t ? Dv : 0.f));
    unsigned short hi = f2bs(v);
    unsigned short lo = f2bs(v - bu2f(hi));
    bb[5120 + t * 40 + m] = hi;
    bb[6400 + t * 40 + m] = lo;
  }
  #pragma unroll
  for (int i = 0; i < 8; ++i) {     // WT: 2048 entries
    int idx = tid + i * 256;
    int t = idx >> 6, k = idx & 63, n = k >> 1;
    float tp = (float)(t + 1);
    float e = expf(dta_s[n].x * tp);
    float pr = e * cosf(dta_s[n].y * tp), pi = e * sinf(dta_s[n].y * tp);
    float cwr = cd_s[n].x * pr - cd_s[n].y * pi;
    float cwi = cd_s[n].x * pi + cd_s[n].y * pr;
    float v = (k & 1) ? -2.f * cwi : 2.f * cwr;
    unsigned short hi = f2bs(v);
    unsigned short lo = f2bs(v - bu2f(hi));
    bb[7680 + t * 72 + k] = hi;
    bb[9984 + t * 72 + k] = lo;
  }
}

// ---------------- S4D conv v6: v5 + HW packed bf16 converts in fixup/epilogue ----------------
__global__ __launch_bounds__(256, 3) void s4d_conv6_kernel(
    const bf16* __restrict__ u_g, bf16* __restrict__ y_g,
    const unsigned short* __restrict__ Bg, const float2* __restrict__ wTg) {
  static __shared__ char __align__(16) sm[51456];
  constexpr int O_U = 0;
  constexpr int O_SH = 10240;
  constexpr int O_SL = 28672;
  constexpr int O_WT = 47104;
  constexpr int O_GE = 47360;
  constexpr int O_GT = 49408;

  int tid = threadIdx.x;
  int lane = tid & 63, wv = tid >> 6;
  int r15 = lane & 15, quad = lane >> 4;
  int bh = blockIdx.x, hh = bh & 127;
  const char* bg0 = (const char*)(Bg + (size_t)hh * 12288);

  {
    const uint4* ug = (const uint4*)(u_g + (size_t)bh * L);
    #pragma unroll
    for (int r = 0; r < 2; ++r) {
      int idx = tid + r * 256;
      *(uint4*)(sm + O_U + (idx >> 2) * 80 + (idx & 3) * 16) = ug[idx];
    }
  }
  if (tid < 32) *(float2*)(sm + O_WT + tid * 8) = wTg[hh * 32 + tid];

  short8v bvh[4], bvl[4];
  #pragma unroll
  for (int nt = 0; nt < 4; ++nt) {
    bvh[nt] = *(const short8v*)(bg0 + 0    + (nt * 16 + r15) * 80 + quad * 16);
    bvl[nt] = *(const short8v*)(bg0 + 5120 + (nt * 16 + r15) * 80 + quad * 16);
  }
  __syncthreads();

  // ---- phase P
  short8v aU0 = *(const short8v*)(sm + O_U + ((wv * 2 + 0) * 16 + r15) * 80 + quad * 16);
  short8v aU1 = *(const short8v*)(sm + O_U + ((wv * 2 + 1) * 16 + r15) * 80 + quad * 16);
  floatx4 cp[2][4];
  #pragma unroll
  for (int mt = 0; mt < 2; ++mt)
    #pragma unroll
    for (int nt = 0; nt < 4; ++nt) cp[mt][nt] = (floatx4){0.f, 0.f, 0.f, 0.f};
  #pragma unroll
  for (int nt = 0; nt < 4; ++nt) {
    cp[0][nt] = __builtin_amdgcn_mfma_f32_16x16x32_bf16(aU0, bvh[nt], cp[0][nt], 0, 0, 0);
    cp[0][nt] = __builtin_amdgcn_mfma_f32_16x16x32_bf16(aU0, bvl[nt], cp[0][nt], 0, 0, 0);
    cp[1][nt] = __builtin_amdgcn_mfma_f32_16x16x32_bf16(aU1, bvh[nt], cp[1][nt], 0, 0, 0);
    cp[1][nt] = __builtin_amdgcn_mfma_f32_16x16x32_bf16(aU1, bvl[nt], cp[1][nt], 0, 0, 0);
  }
  #pragma unroll
  for (int mt = 0; mt < 2; ++mt)
    #pragma unroll
    for (int nt = 0; nt < 4; ++nt) {
      int n2 = nt * 16 + r15;
      int off = ((n2 & 1) ? O_SL : O_SH) + (n2 >> 1) * 4;
      #pragma unroll
      for (int rg = 0; rg < 4; ++rg) {
        int c = (wv * 2 + mt) * 16 + quad * 4 + rg;
        *(float*)(sm + off + c * 144) = cp[mt][nt][rg];
      }
    }
  __syncthreads();

  // ---- scan A: batched loads, recurrence in regs, exclusive prefixes HELD in regs
  int sg = tid >> 5, sn = tid & 31;
  float2 swt = *(const float2*)(sm + O_WT + sn * 8);
  float epr[16], epi[16];
  {
    float pr_[16], pi_[16];
    #pragma unroll
    for (int k = 0; k < 16; ++k) {
      pr_[k] = *(const float*)(sm + O_SH + (sg * 16 + k) * 144 + sn * 4);
      pi_[k] = *(const float*)(sm + O_SL + (sg * 16 + k) * 144 + sn * 4);
    }
    float rr = 0.f, ri = 0.f;
    #pragma unroll
    for (int k = 0; k < 16; ++k) {
      epr[k] = rr; epi[k] = ri;
      float nr = swt.x * rr - swt.y * ri + pr_[k];
      ri = swt.x * ri + swt.y * rr + pi_[k];
      rr = nr;
    }
    *(float2*)(sm + O_GT + (sg * 32 + sn) * 8) = make_float2(rr, ri);
  }
  __syncthreads();
  // ---- scan B: serial over 8 groups; wT^16 via 4 squarings
  if (tid < 32) {
    float2 wt = *(const float2*)(sm + O_WT + tid * 8);
    float w2r = wt.x * wt.x - wt.y * wt.y,   w2i = 2.f * wt.x * wt.y;
    float w4r = w2r * w2r - w2i * w2i,       w4i = 2.f * w2r * w2i;
    float w8r = w4r * w4r - w4i * w4i,       w8i = 2.f * w4r * w4i;
    float w16r = w8r * w8r - w8i * w8i,      w16i = 2.f * w8r * w8i;
    float rr = 0.f, ri = 0.f;
    for (int g = 0; g < 8; ++g) {
      *(float2*)(sm + O_GE + (g * 32 + tid) * 8) = make_float2(rr, ri);
      float2 gt = *(const float2*)(sm + O_GT + (g * 32 + tid) * 8);
      float nr = w16r * rr - w16i * ri + gt.x;
      ri = w16r * ri + w16i * rr + gt.y;
      rr = nr;
    }
  }
  __syncthreads();
  // ---- fixup: E[c] = prefix + wT^k * GE[g]; HW packed-cvt hi/lo write
  {
    float2 ge = *(const float2*)(sm + O_GE + (sg * 32 + sn) * 8);
    float ar = ge.x, ai = ge.y;   // wT^0 * GE
    #pragma unroll
    for (int k = 0; k < 16; ++k) {
      int c = sg * 16 + k;
      float er = epr[k] + ar;
      float ei = epi[k] + ai;
      unsigned uh = pack2(er, ei);
      *(unsigned*)(sm + O_SH + c * 144 + sn * 4) = uh;
      *(unsigned*)(sm + O_SL + c * 144 + sn * 4) =
          pack2(er - bu2f(uh & 0xffffu), ei - bu2f(uh >> 16));
      float nr = ar * swt.x - ai * swt.y;   // advance wT^k * GE
      ai = ar * swt.y + ai * swt.x;
      ar = nr;
    }
  }
  __syncthreads();

  // ---- Toeplitz + modal MFMAs (K/W frags direct from L2)
  floatx4 acc[2][2];
  #pragma unroll
  for (int mt = 0; mt < 2; ++mt)
    #pragma unroll
    for (int nt = 0; nt < 2; ++nt) acc[mt][nt] = (floatx4){0.f, 0.f, 0.f, 0.f};
  #pragma unroll
  for (int nt = 0; nt < 2; ++nt) {
    short8v kh = *(const short8v*)(bg0 + 10240 + (nt * 16 + r15) * 80 + quad * 16);
    short8v kl = *(const short8v*)(bg0 + 12800 + (nt * 16 + r15) * 80 + quad * 16);
    acc[0][nt] = __builtin_amdgcn_mfma_f32_16x16x32_bf16(aU0, kh, acc[0][nt], 0, 0, 0);
    acc[0][nt] = __builtin_amdgcn_mfma_f32_16x16x32_bf16(aU0, kl, acc[0][nt], 0, 0, 0);
    acc[1][nt] = __builtin_amdgcn_mfma_f32_16x16x32_bf16(aU1, kh, acc[1][nt], 0, 0, 0);
    acc[1][nt] = __builtin_amdgcn_mfma_f32_16x16x32_bf16(aU1, kl, acc[1][nt], 0, 0, 0);
  }
  #pragma unroll
  for (int ks = 0; ks < 2; ++ks) {
    short8v sh0 = *(const short8v*)(sm + O_SH + ((wv * 2 + 0) * 16 + r15) * 144 + ks * 64 + quad * 16);
    short8v sh1 = *(const short8v*)(sm + O_SH + ((wv * 2 + 1) * 16 + r15) * 144 + ks * 64 + quad * 16);
    short8v sl0 = *(const short8v*)(sm + O_SL + ((wv * 2 + 0) * 16 + r15) * 144 + ks * 64 + quad * 16);
    short8v sl1 = *(const short8v*)(sm + O_SL + ((wv * 2 + 1) * 16 + r15) * 144 + ks * 64 + quad * 16);
    #pragma unroll
    for (int nt = 0; nt < 2; ++nt) {
      short8v wh = *(const short8v*)(bg0 + 15360 + (nt * 16 + r15) * 144 + ks * 64 + quad * 16);
      short8v wl = *(const short8v*)(bg0 + 19968 + (nt * 16 + r15) * 144 + ks * 64 + quad * 16);
      acc[0][nt] = __builtin_amdgcn_mfma_f32_16x16x32_bf16(sh0, wh, acc[0][nt], 0, 0, 0);
      acc[0][nt] = __builtin_amdgcn_mfma_f32_16x16x32_bf16(sh0, wl, acc[0][nt], 0, 0, 0);
      acc[0][nt] = __builtin_amdgcn_mfma_f32_16x16x32_bf16(sl0, wh, acc[0][nt], 0, 0, 0);
      acc[1][nt] = __builtin_amdgcn_mfma_f32_16x16x32_bf16(sh1, wh, acc[1][nt], 0, 0, 0);
      acc[1][nt] = __builtin_amdgcn_mfma_f32_16x16x32_bf16(sh1, wl, acc[1][nt], 0, 0, 0);
      acc[1][nt] = __builtin_amdgcn_mfma_f32_16x16x32_bf16(sl1, wh, acc[1][nt], 0, 0, 0);
    }
  }

  #pragma unroll
  for (int mt = 0; mt < 2; ++mt)
    #pragma unroll
    for (int nt = 0; nt < 2; ++nt)
      #pragma unroll
      for (int rg = 0; rg < 4; ++rg) {
        int c = (wv * 2 + mt) * 16 + quad * 4 + rg;
        int t = nt * 16 + r15;
        float v = acc[mt][nt][rg];
        v = 0.5f * v * (1.f + erff(v * 0.70710678118654752f));
        *(unsigned short*)(sm + O_U + (c * 32 + t) * 2) = f2bs(v);
      }
  __syncthreads();
  {
    uint4* yo = (uint4*)(y_g + (size_t)bh * L);
    #pragma unroll
    for (int r = 0; r < 2; ++r) {
      int idx = tid + r * 256;
      yo[idx] = *(const uint4*)(sm + O_U + idx * 16);
    }
  }
}

// ------- glu_ln v11: R15/R16 structure + HW packed converts in z-write and store -------
__global__ __launch_bounds__(256, 2) void glu_ln11_kernel(
    const unsigned short* __restrict__ y_g, unsigned short* __restrict__ h_g,
    const unsigned short* __restrict__ Wb,  // layer: [hi 256x128] shorts
    const float* __restrict__ ob, const float* __restrict__ lg,
    const float* __restrict__ lb) {
  static __shared__ char __align__(16) sm[36864];
  constexpr int O_Y = 0;        // y transposed [64 pos][136 ch-shorts] = 17408 B (row 272 B)
  constexpr int O_H = 17408;    // h natural [128 ch][68 pos-shorts] = 17408 B; z aliases in-place
  constexpr int O_P = 34816;    // LN partials [4 waves][64 pos] float2 = 2048 B

  int tid = threadIdx.x;
  int wv = tid >> 6, lane = tid & 63, r15 = lane & 15, quad = lane >> 4;
  int b = blockIdx.x >> 4, seg = blockIdx.x & 15;

  float ba[2][4], bgl[2][4];
  #pragma unroll
  for (int i = 0; i < 2; ++i) {
    int ch0 = (2 * wv + i) * 16 + quad * 4;
    #pragma unroll
    for (int rg = 0; rg < 4; ++rg) {
      ba[i][rg]  = ob[ch0 + rg];
      bgl[i][rg] = ob[128 + ch0 + rg];
    }
  }

  for (int t = 0; t < 4; ++t) {
    int l0 = seg * 256 + t * 64;
    {
      int k = tid >> 1, half = tid & 1;
      const uint4* src = (const uint4*)(y_g + ((size_t)(b * H + k)) * L + l0 + half * 32);
      unsigned short sarr[32];
      uint4* sp = (uint4*)sarr;
      sp[0] = src[0]; sp[1] = src[1]; sp[2] = src[2]; sp[3] = src[3];
      #pragma unroll
      for (int j = 0; j < 32; ++j)
        *(unsigned short*)(sm + O_Y + (half * 32 + j) * 272 + k * 2) = sarr[j];
    }
    {
      #pragma unroll
      for (int i = 0; i < 4; ++i) {
        int id = tid + i * 256;           // 0..1023
        int ch = id >> 3, part = id & 7;
        uint4 v = *(const uint4*)(h_g + ((size_t)(b * H + ch)) * L + l0 + part * 8);
        *(uint4*)(sm + O_H + ch * 136 + part * 16) = v;
      }
    }
    __syncthreads();   // A

    float s1[4] = {0.f, 0.f, 0.f, 0.f}, s2[4] = {0.f, 0.f, 0.f, 0.f};
    #pragma unroll
    for (int pt = 0; pt < 4; ++pt) {
      short8v bf[4];
      #pragma unroll
      for (int ks = 0; ks < 4; ++ks)
        bf[ks] = *(const short8v*)(sm + O_Y + (pt * 16 + r15) * 272 + ks * 64 + quad * 16);
      int pos = pt * 16 + r15;
      #pragma unroll
      for (int i = 0; i < 2; ++i) {
        int ch0 = (2 * wv + i) * 16 + quad * 4;
        const unsigned short* wa = Wb + (size_t)((2 * wv + i) * 16 + r15) * 128 + quad * 8;
        floatx4 acca = (floatx4){0.f, 0.f, 0.f, 0.f};
        #pragma unroll
        for (int ks = 0; ks < 4; ++ks) {
          short8v wf = *(const short8v*)(wa + ks * 32);
          acca = __builtin_amdgcn_mfma_f32_16x16x32_bf16(wf, bf[ks], acca, 0, 0, 0);
        }
        const unsigned short* wg = Wb + (size_t)((8 + 2 * wv + i) * 16 + r15) * 128 + quad * 8;
        floatx4 accg = (floatx4){0.f, 0.f, 0.f, 0.f};
        #pragma unroll
        for (int ks = 0; ks < 4; ++ks) {
          short8v wf = *(const short8v*)(wg + ks * 32);
          accg = __builtin_amdgcn_mfma_f32_16x16x32_bf16(wf, bf[ks], accg, 0, 0, 0);
        }
        #pragma unroll
        for (int rg = 0; rg < 4; ++rg) {
          float a = acca[rg] + ba[i][rg];
          float g = accg[rg] + bgl[i][rg];
          float zz = a / (1.f + expf(-g));
          char* slot = sm + O_H + (ch0 + rg) * 136 + pos * 2;
          zz += bu2f(*(const unsigned short*)slot);   // residual read
          s1[pt] += zz;
          s2[pt] += zz * zz;
          *(unsigned short*)slot = f2bs(zz);          // z write, same slot, same lane
        }
      }
    }
    #pragma unroll
    for (int pt = 0; pt < 4; ++pt) {
      s1[pt] += __shfl_xor(s1[pt], 16, 64); s1[pt] += __shfl_xor(s1[pt], 32, 64);
      s2[pt] += __shfl_xor(s2[pt], 16, 64); s2[pt] += __shfl_xor(s2[pt], 32, 64);
    }
    if (quad == 0) {
      #pragma unroll
      for (int pt = 0; pt < 4; ++pt)
        *(float2*)(sm + O_P + (wv * 64 + pt * 16 + r15) * 8) = make_float2(s1[pt], s2[pt]);
    }
    __syncthreads();   // B

    if (tid < 64) {
      float a1 = 0.f, a2 = 0.f;
      #pragma unroll
      for (int w = 0; w < 4; ++w) {
        float2 p = *(const float2*)(sm + O_P + (w * 64 + tid) * 8);
        a1 += p.x; a2 += p.y;
      }
      float m = a1 * (1.f / H);
      float var = a2 * (1.f / H) - m * m;
      if (var < 0.f) var = 0.f;
      *(float2*)(sm + O_P + tid * 8) = make_float2(m, rsqrtf(var + 1e-5f));
    }
    __syncthreads();   // C

    {
      int ch = tid >> 1, half = tid & 1;
      float gg = lg[ch], bb2 = lb[ch];
      unsigned outw[16];
      #pragma unroll
      for (int j = 0; j < 16; ++j) {
        int p0 = half * 32 + 2 * j;
        float z0 = bu2f(*(const unsigned short*)(sm + O_H + ch * 136 + p0 * 2));
        float z1 = bu2f(*(const unsigned short*)(sm + O_H + ch * 136 + p0 * 2 + 2));
        float2 m0 = *(const float2*)(sm + O_P + p0 * 8);
        float2 m1 = *(const float2*)(sm + O_P + (p0 + 1) * 8);
        outw[j] = pack2((z0 - m0.x) * m0.y * gg + bb2,
                        (z1 - m1.x) * m1.y * gg + bb2);
      }
      uint4* dst = (uint4*)(h_g + ((size_t)(b * H + ch)) * L + l0 + half * 32);
      #pragma unroll
      for (int j = 0; j < 4; ++j)
        dst[j] = *(const uint4*)(&outw[j * 4]);
    }
    __syncthreads();   // D
  }
}

__global__ __launch_bounds__(256) void pool_kernel(const bf16* __restrict__ h_g,
                                                   float* __restrict__ pooled) {
  int bh = blockIdx.x;
  const bf16* row = h_g + (size_t)bh * L;
  float s = 0.f;
  for (int l = threadIdx.x; l < L; l += 256) s += b2f(row[l]);
  for (int off = 32; off > 0; off >>= 1) s += __shfl_down(s, off);
  __shared__ float wsum[4];
  int lane = threadIdx.x & 63, wv = threadIdx.x >> 6;
  if (lane == 0) wsum[wv] = s;
  __syncthreads();
  if (threadIdx.x == 0)
    pooled[bh] = (wsum[0] + wsum[1] + wsum[2] + wsum[3]) * (1.f / L);
}

__global__ void head_kernel(const float* __restrict__ pooled,
                            const float* __restrict__ head_W,
                            const float* __restrict__ head_b,
                            float* __restrict__ out) {
  int tid = threadIdx.x;
  if (tid >= B * 2) return;
  int b = tid >> 1, o = tid & 1;
  float acc = head_b[o];
  for (int ch = 0; ch < H; ++ch)
    acc += pooled[b * H + ch] * head_W[ch * 2 + o];
  out[tid] = acc;
}

extern "C" void kernel_launch(void* const* d_in, const int* in_sizes, int n_in,
                              void* d_out, int out_size, void* d_ws, size_t ws_size,
                              hipStream_t stream) {
  const float* x          = (const float*)d_in[0];
  const float* enc_W      = (const float*)d_in[1];
  const float* enc_b      = (const float*)d_in[2];
  const float* log_dt     = (const float*)d_in[3];
  const float* C_re       = (const float*)d_in[4];
  const float* C_im       = (const float*)d_in[5];
  const float* log_A_real = (const float*)d_in[6];
  const float* A_imag     = (const float*)d_in[7];
  const float* Dp         = (const float*)d_in[8];
  const float* out_W      = (const float*)d_in[9];
  const float* out_b      = (const float*)d_in[10];
  const float* ln_g       = (const float*)d_in[11];
  const float* ln_b       = (const float*)d_in[12];
  const float* head_W     = (const float*)d_in[13];
  const float* head_b     = (const float*)d_in[14];

  // ws (~84.6 MB): hbuf bf16 32MB | ybuf bf16 32MB | Wb 1.5MB | pooled 16KB |
  //                Bg (all layers) 18.9MB | wTg (all layers) 196KB
  bf16* hbuf = (bf16*)d_ws;
  bf16* ybuf = hbuf + (size_t)B * H * L;
  unsigned short* Wb = (unsigned short*)(ybuf + (size_t)B * H * L);
  float* pooled = (float*)(Wb + (size_t)NL * 65536);
  unsigned short* Bg = (unsigned short*)(pooled + B * H);
  float2* wTg = (float2*)(Bg + (size_t)NL * H * 12288);

  encoder_kernel<<<B * H, 256, 0, stream>>>(x, enc_W, enc_b, hbuf);
  w_prep_kernel<<<(NL * 2 * H * H + 255) / 256, 256, 0, stream>>>(out_W, Wb);
  s4d_prep_all_kernel<<<NL * H, 256, 0, stream>>>(log_dt, C_re, C_im, log_A_real,
                                                  A_imag, Dp, Bg, wTg);

  for (int layer = 0; layer < NL; ++layer) {
    s4d_conv6_kernel<<<B * H, 256, 0, stream>>>(
        hbuf, ybuf, Bg + (size_t)layer * H * 12288, wTg + (size_t)layer * H * NC);
    glu_ln11_kernel<<<B * 16, 256, 0, stream>>>(
        (const unsigned short*)ybuf, (unsigned short*)hbuf,
        Wb + (size_t)layer * 65536, out_b + layer * 2 * H,
        ln_g + layer * H, ln_b + layer * H);
  }

  pool_kernel<<<B * H, 256, 0, stream>>>(hbuf, pooled);
  head_kernel<<<1, 64, 0, stream>>>(pooled, head_W, head_b, (float*)d_out);
}

// Round 19
// 587.385 us; speedup vs baseline: 1.6954x; 1.0473x over previous
//
#include <hip/hip_runtime.h>
#include <hip/hip_bf16.h>

#define B 32
#define H 128
#define L 4096
#define NC 32
#define NL 6
#define NCHUNK 128

typedef __hip_bfloat16 bf16;
typedef __attribute__((ext_vector_type(8))) short short8v;   // 8 bf16 (4 VGPR)
typedef __attribute__((ext_vector_type(4))) float floatx4;   // MFMA C/D

__device__ __forceinline__ float b2f(bf16 v) { return __bfloat162float(v); }
__device__ __forceinline__ float bu2f(unsigned int u) {
  union { unsigned int i; float f; } v; v.i = u << 16; return v.f;
}
// float -> bf16 bits via HW RNE convert
__device__ __forceinline__ unsigned short f2bs(float f) {
  bf16 b = __float2bfloat16(f);
  union { bf16 h; unsigned short s; } cv; cv.h = b; return cv.s;
}
// two floats -> packed bf16 dword (a low, b high) via v_cvt_pk_bf16_f32
__device__ __forceinline__ unsigned pack2(float a, float b) {
  union { __hip_bfloat162 h; unsigned u; } cv;
  cv.h = __float22bfloat162_rn(make_float2(a, b));
  return cv.u;
}

// ---------------- encoder ----------------
__global__ void encoder_kernel(const float* __restrict__ x, const float* __restrict__ enc_W,
                               const float* __restrict__ enc_b, bf16* __restrict__ h) {
  int blk = blockIdx.x;
  int b = blk >> 7, ch = blk & 127;
  float w0 = enc_W[ch];
  float w1 = enc_W[H + ch];
  float bb = enc_b[ch];
  const float* x0 = x + (size_t)b * 2 * L;
  const float* x1 = x0 + L;
  bf16* out = h + ((size_t)b * H + ch) * L;
  for (int l = threadIdx.x; l < L; l += blockDim.x)
    out[l] = __float2bfloat16(x0[l] * w0 + x1[l] * w1 + bb);
}

// Wb[l][hl][o][k]: hi/lo bf16 split of out_W[l][o][k]; per-layer stride 65536
__global__ void w_prep_kernel(const float* __restrict__ out_W, unsigned short* __restrict__ Wb) {
  int idx = blockIdx.x * 256 + threadIdx.x;
  if (idx >= NL * 2 * H * H) return;
  int l = idx / (2 * H * H);
  int rem = idx % (2 * H * H);
  float v = out_W[idx];
  unsigned short hi = f2bs(v);
  unsigned short lo = f2bs(v - bu2f(hi));
  Wb[(size_t)l * 65536 + rem] = hi;
  Wb[(size_t)l * 65536 + 32768 + rem] = lo;
}

// ---------------- per-(layer,h) B-matrix precompute: ALL LAYERS IN ONE DISPATCH ----------------
__global__ __launch_bounds__(256) void s4d_prep_all_kernel(
    const float* __restrict__ log_dt, const float* __restrict__ C_re,
    const float* __restrict__ C_im, const float* __restrict__ log_A_real,
    const float* __restrict__ A_imag, const float* __restrict__ Dp,
    unsigned short* __restrict__ Bg, float2* __restrict__ wTg) {
  __shared__ float2 dta_s[NC], cd_s[NC];
  __shared__ float K_s[32];
  int lh = blockIdx.x;
  int layer = lh >> 7, h = lh & 127;
  int tid = threadIdx.x;
  if (tid < NC) {
    int n = tid, base = (layer * H + h) * NC + n;
    float dt = expf(log_dt[layer * H + h]);
    float Are = -expf(log_A_real[base]);
    float Aim = A_imag[base];
    float dre = dt * Are, dim = dt * Aim;
    float er = expf(dre);
    float wre = er * cosf(dim), wim = er * sinf(dim);
    float emre = wre - 1.f, emim = wim;   // expm1(dtA)
    float cre = C_re[base], cim = C_im[base];
    float nre = cre * emre - cim * emim, nim = cre * emim + cim * emre;
    float den = Are * Are + Aim * Aim;
    dta_s[n] = make_float2(dre, dim);
    cd_s[n] = make_float2((nre * Are + nim * Aim) / den, (nim * Are - nre * Aim) / den);
    float e32 = expf(dre * 32.f);
    wTg[lh * NC + n] = make_float2(e32 * cosf(dim * 32.f), e32 * sinf(dim * 32.f));
  }
  __syncthreads();
  if (tid < 32) {  // K[tau] = 2 sum_n Re(cd_n w_n^tau)
    float acc = 0.f;
    float tau = (float)tid;
    for (int n = 0; n < NC; ++n) {
      float e = expf(dta_s[n].x * tau);
      float pr = e * cosf(dta_s[n].y * tau), pi = e * sinf(dta_s[n].y * tau);
      acc += cd_s[n].x * pr - cd_s[n].y * pi;
    }
    K_s[tid] = 2.f * acc;
  }
  __syncthreads();
  unsigned short* bb = Bg + (size_t)lh * 12288;
  float Dv = Dp[layer * H + h];
  #pragma unroll
  for (int i = 0; i < 8; ++i) {     // VT: 2048 entries
    int idx = tid + i * 256;
    int n2 = idx >> 5, t = idx & 31, n = n2 >> 1;
    float k = (float)(31 - t);
    float e = expf(dta_s[n].x * k);
    float v = (n2 & 1) ? e * sinf(dta_s[n].y * k) : e * cosf(dta_s[n].y * k);
    unsigned short hi = f2bs(v);
    unsigned short lo = f2bs(v - bu2f(hi));
    bb[n2 * 40 + t] = hi;
    bb[2560 + n2 * 40 + t] = lo;
  }
  #pragma unroll
  for (int i = 0; i < 4; ++i) {     // KT: 1024 entries
    int idx = tid + i * 256;
    int t = idx >> 5, m = idx & 31;
    float v = (m > t) ? 0.f : (K_s[t - m] + (m == t ? Dv : 0.f));
    unsigned short hi = f2bs(v);
    unsigned short lo = f2bs(v - bu2f(hi));
    bb[5120 + t * 40 + m] = hi;
    bb[6400 + t * 40 + m] = lo;
  }
  #pragma unroll
  for (int i = 0; i < 8; ++i) {     // WT: 2048 entries
    int idx = tid + i * 256;
    int t = idx >> 6, k = idx & 63, n = k >> 1;
    float tp = (float)(t + 1);
    float e = expf(dta_s[n].x * tp);
    float pr = e * cosf(dta_s[n].y * tp), pi = e * sinf(dta_s[n].y * tp);
    float cwr = cd_s[n].x * pr - cd_s[n].y * pi;
    float cwi = cd_s[n].x * pi + cd_s[n].y * pr;
    float v = (k & 1) ? -2.f * cwi : 2.f * cwr;
    unsigned short hi = f2bs(v);
    unsigned short lo = f2bs(v - bu2f(hi));
    bb[7680 + t * 72 + k] = hi;
    bb[9984 + t * 72 + k] = lo;
  }
}

// ---------------- S4D conv v7: no U staging (A-frags direct from global), GT/GE in
// S-row pads; LDS 37120 B -> 4 blocks/CU. Epilogue stages y through dead S_hi. ----------
__global__ __launch_bounds__(256, 4) void s4d_conv7_kernel(
    const bf16* __restrict__ u_g, bf16* __restrict__ y_g,
    const unsigned short* __restrict__ Bg, const float2* __restrict__ wTg) {
  static __shared__ char __align__(16) sm[37120];
  constexpr int O_SH = 0;       // scan re / packed hi: 128 rows x 144 B (cols 0..127 + 16 B pad)
  constexpr int O_SL = 18432;   // scan im / packed lo
  constexpr int O_WT = 36864;   // wT [32] float2 = 256 B
  // GT[i] lives in S_hi pad: O_SH + (i>>1)*144 + 128 + (i&1)*8   (i = g*32+n)
  // GE[i] lives in S_lo pad: O_SL + (i>>1)*144 + 128 + (i&1)*8

  int tid = threadIdx.x;
  int lane = tid & 63, wv = tid >> 6;
  int r15 = lane & 15, quad = lane >> 4;
  int bh = blockIdx.x, hh = bh & 127;
  const char* bg0 = (const char*)(Bg + (size_t)hh * 12288);
  const char* ug0 = (const char*)(u_g + (size_t)bh * L);

  if (tid < 32) *(float2*)(sm + O_WT + tid * 8) = wTg[hh * 32 + tid];

  // A-fragments direct from global (fully coalesced 16 B/lane within a 4 KB span)
  short8v aU0 = *(const short8v*)(ug0 + ((wv * 2 + 0) * 16 + r15) * 64 + quad * 16);
  short8v aU1 = *(const short8v*)(ug0 + ((wv * 2 + 1) * 16 + r15) * 64 + quad * 16);
  // V fragments from L2
  short8v bvh[4], bvl[4];
  #pragma unroll
  for (int nt = 0; nt < 4; ++nt) {
    bvh[nt] = *(const short8v*)(bg0 + 0    + (nt * 16 + r15) * 80 + quad * 16);
    bvl[nt] = *(const short8v*)(bg0 + 5120 + (nt * 16 + r15) * 80 + quad * 16);
  }

  // ---- phase P (no barrier needed before: all inputs are regs)
  floatx4 cp[2][4];
  #pragma unroll
  for (int mt = 0; mt < 2; ++mt)
    #pragma unroll
    for (int nt = 0; nt < 4; ++nt) cp[mt][nt] = (floatx4){0.f, 0.f, 0.f, 0.f};
  #pragma unroll
  for (int nt = 0; nt < 4; ++nt) {
    cp[0][nt] = __builtin_amdgcn_mfma_f32_16x16x32_bf16(aU0, bvh[nt], cp[0][nt], 0, 0, 0);
    cp[0][nt] = __builtin_amdgcn_mfma_f32_16x16x32_bf16(aU0, bvl[nt], cp[0][nt], 0, 0, 0);
    cp[1][nt] = __builtin_amdgcn_mfma_f32_16x16x32_bf16(aU1, bvh[nt], cp[1][nt], 0, 0, 0);
    cp[1][nt] = __builtin_amdgcn_mfma_f32_16x16x32_bf16(aU1, bvl[nt], cp[1][nt], 0, 0, 0);
  }
  #pragma unroll
  for (int mt = 0; mt < 2; ++mt)
    #pragma unroll
    for (int nt = 0; nt < 4; ++nt) {
      int n2 = nt * 16 + r15;
      int off = ((n2 & 1) ? O_SL : O_SH) + (n2 >> 1) * 4;
      #pragma unroll
      for (int rg = 0; rg < 4; ++rg) {
        int c = (wv * 2 + mt) * 16 + quad * 4 + rg;
        *(float*)(sm + off + c * 144) = cp[mt][nt][rg];
      }
    }
  __syncthreads();   // P stores + wT visible

  // ---- scan A: batched loads, recurrence in regs, prefixes HELD in regs
  int sg = tid >> 5, sn = tid & 31;
  float2 swt = *(const float2*)(sm + O_WT + sn * 8);
  float epr[16], epi[16];
  {
    float pr_[16], pi_[16];
    #pragma unroll
    for (int k = 0; k < 16; ++k) {
      pr_[k] = *(const float*)(sm + O_SH + (sg * 16 + k) * 144 + sn * 4);
      pi_[k] = *(const float*)(sm + O_SL + (sg * 16 + k) * 144 + sn * 4);
    }
    float rr = 0.f, ri = 0.f;
    #pragma unroll
    for (int k = 0; k < 16; ++k) {
      epr[k] = rr; epi[k] = ri;
      float nr = swt.x * rr - swt.y * ri + pr_[k];
      ri = swt.x * ri + swt.y * rr + pi_[k];
      rr = nr;
    }
    int i = sg * 32 + sn;
    *(float2*)(sm + O_SH + (i >> 1) * 144 + 128 + (i & 1) * 8) = make_float2(rr, ri);  // GT
  }
  __syncthreads();
  // ---- scan B: serial over 8 groups; wT^16 via 4 squarings
  if (tid < 32) {
    float2 wt = *(const float2*)(sm + O_WT + tid * 8);
    float w2r = wt.x * wt.x - wt.y * wt.y,   w2i = 2.f * wt.x * wt.y;
    float w4r = w2r * w2r - w2i * w2i,       w4i = 2.f * w2r * w2i;
    float w8r = w4r * w4r - w4i * w4i,       w8i = 2.f * w4r * w4i;
    float w16r = w8r * w8r - w8i * w8i,      w16i = 2.f * w8r * w8i;
    float rr = 0.f, ri = 0.f;
    for (int g = 0; g < 8; ++g) {
      int i = g * 32 + tid;
      *(float2*)(sm + O_SL + (i >> 1) * 144 + 128 + (i & 1) * 8) = make_float2(rr, ri);  // GE
      float2 gt = *(const float2*)(sm + O_SH + (i >> 1) * 144 + 128 + (i & 1) * 8);
      float nr = w16r * rr - w16i * ri + gt.x;
      ri = w16r * ri + w16i * rr + gt.y;
      rr = nr;
    }
  }
  __syncthreads();
  // ---- fixup: E[c] = prefix + wT^k * GE[g]; HW packed-cvt hi/lo write
  {
    int i = sg * 32 + sn;
    float2 ge = *(const float2*)(sm + O_SL + (i >> 1) * 144 + 128 + (i & 1) * 8);
    float ar = ge.x, ai = ge.y;   // wT^0 * GE
    #pragma unroll
    for (int k = 0; k < 16; ++k) {
      int c = sg * 16 + k;
      float er = epr[k] + ar;
      float ei = epi[k] + ai;
      unsigned uh = pack2(er, ei);
      *(unsigned*)(sm + O_SH + c * 144 + sn * 4) = uh;
      *(unsigned*)(sm + O_SL + c * 144 + sn * 4) =
          pack2(er - bu2f(uh & 0xffffu), ei - bu2f(uh >> 16));
      float nr = ar * swt.x - ai * swt.y;   // advance wT^k * GE
      ai = ar * swt.y + ai * swt.x;
      ar = nr;
    }
  }
  __syncthreads();

  // ---- Toeplitz + modal MFMAs (K/W frags direct from L2)
  floatx4 acc[2][2];
  #pragma unroll
  for (int mt = 0; mt < 2; ++mt)
    #pragma unroll
    for (int nt = 0; nt < 2; ++nt) acc[mt][nt] = (floatx4){0.f, 0.f, 0.f, 0.f};
  #pragma unroll
  for (int nt = 0; nt < 2; ++nt) {
    short8v kh = *(const short8v*)(bg0 + 10240 + (nt * 16 + r15) * 80 + quad * 16);
    short8v kl = *(const short8v*)(bg0 + 12800 + (nt * 16 + r15) * 80 + quad * 16);
    acc[0][nt] = __builtin_amdgcn_mfma_f32_16x16x32_bf16(aU0, kh, acc[0][nt], 0, 0, 0);
    acc[0][nt] = __builtin_amdgcn_mfma_f32_16x16x32_bf16(aU0, kl, acc[0][nt], 0, 0, 0);
    acc[1][nt] = __builtin_amdgcn_mfma_f32_16x16x32_bf16(aU1, kh, acc[1][nt], 0, 0, 0);
    acc[1][nt] = __builtin_amdgcn_mfma_f32_16x16x32_bf16(aU1, kl, acc[1][nt], 0, 0, 0);
  }
  #pragma unroll
  for (int ks = 0; ks < 2; ++ks) {
    short8v sh0 = *(const short8v*)(sm + O_SH + ((wv * 2 + 0) * 16 + r15) * 144 + ks * 64 + quad * 16);
    short8v sh1 = *(const short8v*)(sm + O_SH + ((wv * 2 + 1) * 16 + r15) * 144 + ks * 64 + quad * 16);
    short8v sl0 = *(const short8v*)(sm + O_SL + ((wv * 2 + 0) * 16 + r15) * 144 + ks * 64 + quad * 16);
    short8v sl1 = *(const short8v*)(sm + O_SL + ((wv * 2 + 1) * 16 + r15) * 144 + ks * 64 + quad * 16);
    #pragma unroll
    for (int nt = 0; nt < 2; ++nt) {
      short8v wh = *(const short8v*)(bg0 + 15360 + (nt * 16 + r15) * 144 + ks * 64 + quad * 16);
      short8v wl = *(const short8v*)(bg0 + 19968 + (nt * 16 + r15) * 144 + ks * 64 + quad * 16);
      acc[0][nt] = __builtin_amdgcn_mfma_f32_16x16x32_bf16(sh0, wh, acc[0][nt], 0, 0, 0);
      acc[0][nt] = __builtin_amdgcn_mfma_f32_16x16x32_bf16(sh0, wl, acc[0][nt], 0, 0, 0);
      acc[0][nt] = __builtin_amdgcn_mfma_f32_16x16x32_bf16(sl0, wh, acc[0][nt], 0, 0, 0);
      acc[1][nt] = __builtin_amdgcn_mfma_f32_16x16x32_bf16(sh1, wh, acc[1][nt], 0, 0, 0);
      acc[1][nt] = __builtin_amdgcn_mfma_f32_16x16x32_bf16(sh1, wl, acc[1][nt], 0, 0, 0);
      acc[1][nt] = __builtin_amdgcn_mfma_f32_16x16x32_bf16(sl1, wh, acc[1][nt], 0, 0, 0);
    }
  }
  __syncthreads();   // all S reads done; reuse S_hi base as y staging (8192 B)

  #pragma unroll
  for (int mt = 0; mt < 2; ++mt)
    #pragma unroll
    for (int nt = 0; nt < 2; ++nt)
      #pragma unroll
      for (int rg = 0; rg < 4; ++rg) {
        int c = (wv * 2 + mt) * 16 + quad * 4 + rg;
        int t = nt * 16 + r15;
        float v = acc[mt][nt][rg];
        v = 0.5f * v * (1.f + erff(v * 0.70710678118654752f));
        *(unsigned short*)(sm + O_SH + (c * 32 + t) * 2) = f2bs(v);
      }
  __syncthreads();
  {
    uint4* yo = (uint4*)(y_g + (size_t)bh * L);
    #pragma unroll
    for (int r = 0; r < 2; ++r) {
      int idx = tid + r * 256;
      yo[idx] = *(const uint4*)(sm + O_SH + idx * 16);
    }
  }
}

// ------- glu_ln v11 (R18, proven) -------
__global__ __launch_bounds__(256, 2) void glu_ln11_kernel(
    const unsigned short* __restrict__ y_g, unsigned short* __restrict__ h_g,
    const unsigned short* __restrict__ Wb,  // layer: [hi 256x128] shorts
    const float* __restrict__ ob, const float* __restrict__ lg,
    const float* __restrict__ lb) {
  static __shared__ char __align__(16) sm[36864];
  constexpr int O_Y = 0;        // y transposed [64 pos][136 ch-shorts] = 17408 B (row 272 B)
  constexpr int O_H = 17408;    // h natural [128 ch][68 pos-shorts] = 17408 B; z aliases in-place
  constexpr int O_P = 34816;    // LN partials [4 waves][64 pos] float2 = 2048 B

  int tid = threadIdx.x;
  int wv = tid >> 6, lane = tid & 63, r15 = lane & 15, quad = lane >> 4;
  int b = blockIdx.x >> 4, seg = blockIdx.x & 15;

  float ba[2][4], bgl[2][4];
  #pragma unroll
  for (int i = 0; i < 2; ++i) {
    int ch0 = (2 * wv + i) * 16 + quad * 4;
    #pragma unroll
    for (int rg = 0; rg < 4; ++rg) {
      ba[i][rg]  = ob[ch0 + rg];
      bgl[i][rg] = ob[128 + ch0 + rg];
    }
  }

  for (int t = 0; t < 4; ++t) {
    int l0 = seg * 256 + t * 64;
    {
      int k = tid >> 1, half = tid & 1;
      const uint4* src = (const uint4*)(y_g + ((size_t)(b * H + k)) * L + l0 + half * 32);
      unsigned short sarr[32];
      uint4* sp = (uint4*)sarr;
      sp[0] = src[0]; sp[1] = src[1]; sp[2] = src[2]; sp[3] = src[3];
      #pragma unroll
      for (int j = 0; j < 32; ++j)
        *(unsigned short*)(sm + O_Y + (half * 32 + j) * 272 + k * 2) = sarr[j];
    }
    {
      #pragma unroll
      for (int i = 0; i < 4; ++i) {
        int id = tid + i * 256;           // 0..1023
        int ch = id >> 3, part = id & 7;
        uint4 v = *(const uint4*)(h_g + ((size_t)(b * H + ch)) * L + l0 + part * 8);
        *(uint4*)(sm + O_H + ch * 136 + part * 16) = v;
      }
    }
    __syncthreads();   // A

    float s1[4] = {0.f, 0.f, 0.f, 0.f}, s2[4] = {0.f, 0.f, 0.f, 0.f};
    #pragma unroll
    for (int pt = 0; pt < 4; ++pt) {
      short8v bf[4];
      #pragma unroll
      for (int ks = 0; ks < 4; ++ks)
        bf[ks] = *(const short8v*)(sm + O_Y + (pt * 16 + r15) * 272 + ks * 64 + quad * 16);
      int pos = pt * 16 + r15;
      #pragma unroll
      for (int i = 0; i < 2; ++i) {
        int ch0 = (2 * wv + i) * 16 + quad * 4;
        const unsigned short* wa = Wb + (size_t)((2 * wv + i) * 16 + r15) * 128 + quad * 8;
        floatx4 acca = (floatx4){0.f, 0.f, 0.f, 0.f};
        #pragma unroll
        for (int ks = 0; ks < 4; ++ks) {
          short8v wf = *(const short8v*)(wa + ks * 32);
          acca = __builtin_amdgcn_mfma_f32_16x16x32_bf16(wf, bf[ks], acca, 0, 0, 0);
        }
        const unsigned short* wg = Wb + (size_t)((8 + 2 * wv + i) * 16 + r15) * 128 + quad * 8;
        floatx4 accg = (floatx4){0.f, 0.f, 0.f, 0.f};
        #pragma unroll
        for (int ks = 0; ks < 4; ++ks) {
          short8v wf = *(const short8v*)(wg + ks * 32);
          accg = __builtin_amdgcn_mfma_f32_16x16x32_bf16(wf, bf[ks], accg, 0, 0, 0);
        }
        #pragma unroll
        for (int rg = 0; rg < 4; ++rg) {
          float a = acca[rg] + ba[i][rg];
          float g = accg[rg] + bgl[i][rg];
          float zz = a / (1.f + expf(-g));
          char* slot = sm + O_H + (ch0 + rg) * 136 + pos * 2;
          zz += bu2f(*(const unsigned short*)slot);   // residual read
          s1[pt] += zz;
          s2[pt] += zz * zz;
          *(unsigned short*)slot = f2bs(zz);          // z write, same slot, same lane
        }
      }
    }
    #pragma unroll
    for (int pt = 0; pt < 4; ++pt) {
      s1[pt] += __shfl_xor(s1[pt], 16, 64); s1[pt] += __shfl_xor(s1[pt], 32, 64);
      s2[pt] += __shfl_xor(s2[pt], 16, 64); s2[pt] += __shfl_xor(s2[pt], 32, 64);
    }
    if (quad == 0) {
      #pragma unroll
      for (int pt = 0; pt < 4; ++pt)
        *(float2*)(sm + O_P + (wv * 64 + pt * 16 + r15) * 8) = make_float2(s1[pt], s2[pt]);
    }
    __syncthreads();   // B

    if (tid < 64) {
      float a1 = 0.f, a2 = 0.f;
      #pragma unroll
      for (int w = 0; w < 4; ++w) {
        float2 p = *(const float2*)(sm + O_P + (w * 64 + tid) * 8);
        a1 += p.x; a2 += p.y;
      }
      float m = a1 * (1.f / H);
      float var = a2 * (1.f / H) - m * m;
      if (var < 0.f) var = 0.f;
      *(float2*)(sm + O_P + tid * 8) = make_float2(m, rsqrtf(var + 1e-5f));
    }
    __syncthreads();   // C

    {
      int ch = tid >> 1, half = tid & 1;
      float gg = lg[ch], bb2 = lb[ch];
      unsigned outw[16];
      #pragma unroll
      for (int j = 0; j < 16; ++j) {
        int p0 = half * 32 + 2 * j;
        float z0 = bu2f(*(const unsigned short*)(sm + O_H + ch * 136 + p0 * 2));
        float z1 = bu2f(*(const unsigned short*)(sm + O_H + ch * 136 + p0 * 2 + 2));
        float2 m0 = *(const float2*)(sm + O_P + p0 * 8);
        float2 m1 = *(const float2*)(sm + O_P + (p0 + 1) * 8);
        outw[j] = pack2((z0 - m0.x) * m0.y * gg + bb2,
                        (z1 - m1.x) * m1.y * gg + bb2);
      }
      uint4* dst = (uint4*)(h_g + ((size_t)(b * H + ch)) * L + l0 + half * 32);
      #pragma unroll
      for (int j = 0; j < 4; ++j)
        dst[j] = *(const uint4*)(&outw[j * 4]);
    }
    __syncthreads();   // D
  }
}

__global__ __launch_bounds__(256) void pool_kernel(const bf16* __restrict__ h_g,
                                                   float* __restrict__ pooled) {
  int bh = blockIdx.x;
  const bf16* row = h_g + (size_t)bh * L;
  float s = 0.f;
  for (int l = threadIdx.x; l < L; l += 256) s += b2f(row[l]);
  for (int off = 32; off > 0; off >>= 1) s += __shfl_down(s, off);
  __shared__ float wsum[4];
  int lane = threadIdx.x & 63, wv = threadIdx.x >> 6;
  if (lane == 0) wsum[wv] = s;
  __syncthreads();
  if (threadIdx.x == 0)
    pooled[bh] = (wsum[0] + wsum[1] + wsum[2] + wsum[3]) * (1.f / L);
}

__global__ void head_kernel(const float* __restrict__ pooled,
                            const float* __restrict__ head_W,
                            const float* __restrict__ head_b,
                            float* __restrict__ out) {
  int tid = threadIdx.x;
  if (tid >= B * 2) return;
  int b = tid >> 1, o = tid & 1;
  float acc = head_b[o];
  for (int ch = 0; ch < H; ++ch)
    acc += pooled[b * H + ch] * head_W[ch * 2 + o];
  out[tid] = acc;
}

extern "C" void kernel_launch(void* const* d_in, const int* in_sizes, int n_in,
                              void* d_out, int out_size, void* d_ws, size_t ws_size,
                              hipStream_t stream) {
  const float* x          = (const float*)d_in[0];
  const float* enc_W      = (const float*)d_in[1];
  const float* enc_b      = (const float*)d_in[2];
  const float* log_dt     = (const float*)d_in[3];
  const float* C_re       = (const float*)d_in[4];
  const float* C_im       = (const float*)d_in[5];
  const float* log_A_real = (const float*)d_in[6];
  const float* A_imag     = (const float*)d_in[7];
  const float* Dp         = (const float*)d_in[8];
  const float* out_W      = (const float*)d_in[9];
  const float* out_b      = (const float*)d_in[10];
  const float* ln_g       = (const float*)d_in[11];
  const float* ln_b       = (const float*)d_in[12];
  const float* head_W     = (const float*)d_in[13];
  const float* head_b     = (const float*)d_in[14];

  // ws (~84.6 MB): hbuf bf16 32MB | ybuf bf16 32MB | Wb 1.5MB | pooled 16KB |
  //                Bg (all layers) 18.9MB | wTg (all layers) 196KB
  bf16* hbuf = (bf16*)d_ws;
  bf16* ybuf = hbuf + (size_t)B * H * L;
  unsigned short* Wb = (unsigned short*)(ybuf + (size_t)B * H * L);
  float* pooled = (float*)(Wb + (size_t)NL * 65536);
  unsigned short* Bg = (unsigned short*)(pooled + B * H);
  float2* wTg = (float2*)(Bg + (size_t)NL * H * 12288);

  encoder_kernel<<<B * H, 256, 0, stream>>>(x, enc_W, enc_b, hbuf);
  w_prep_kernel<<<(NL * 2 * H * H + 255) / 256, 256, 0, stream>>>(out_W, Wb);
  s4d_prep_all_kernel<<<NL * H, 256, 0, stream>>>(log_dt, C_re, C_im, log_A_real,
                                                  A_imag, Dp, Bg, wTg);

  for (int layer = 0; layer < NL; ++layer) {
    s4d_conv7_kernel<<<B * H, 256, 0, stream>>>(
        hbuf, ybuf, Bg + (size_t)layer * H * 12288, wTg + (size_t)layer * H * NC);
    glu_ln11_kernel<<<B * 16, 256, 0, stream>>>(
        (const unsigned short*)ybuf, (unsigned short*)hbuf,
        Wb + (size_t)layer * 65536, out_b + layer * 2 * H,
        ln_g + layer * H, ln_b + layer * H);
  }

  pool_kernel<<<B * H, 256, 0, stream>>>(hbuf, pooled);
  head_kernel<<<1, 64, 0, stream>>>(pooled, head_W, head_b, (float*)d_out);
}